// Round 1
// baseline (102998.425 us; speedup 1.0000x reference)
//
#include <hip/hip_runtime.h>
#include <math.h>

// ---------------------------------------------------------------------------
// RNNv2: 4-layer stacked tanh RNN, S=2048, H=2048, IN=1024.
//   xin = x @ W_x.T                       (kernel 1, batch GEMM)
//   scan: h_l(t) = tanh(W_h[l] h_l(t-1) + (l? W_hh[l-1] h_{l-1}(t) : xin[t]) + B_h[l])
//                                          (kernel 2, persistent + pipelined diagonal)
//   ys  = H3 @ W_y.T + B_y                (kernel 3, batch GEMM)
// d_out = [ys (S*IN) | h_final (L*H)]
// ---------------------------------------------------------------------------

#define S_LEN 2048
#define IN_SZ 1024
#define HID   2048
#define NLAY  4
#define NWG   256
#define BLK   1024
#define ROWS_PER_WG 32            // HID / (NWG/NLAY)
#define STEPS (S_LEN + NLAY - 1)  // 2051 pipelined wavefront steps

// ---------------- grid barrier (monotonic counter, device scope) -----------
__device__ __forceinline__ void grid_barrier(unsigned int* counter, unsigned int target) {
    __syncthreads();
    if (threadIdx.x == 0) {
        __hip_atomic_fetch_add(counter, 1u, __ATOMIC_ACQ_REL, __HIP_MEMORY_SCOPE_AGENT);
        while (__hip_atomic_load(counter, __ATOMIC_ACQUIRE, __HIP_MEMORY_SCOPE_AGENT) < target) {
            __builtin_amdgcn_s_sleep(1);
        }
    }
    __syncthreads();
}

// ---------------- kernel 2: the sequential scan ----------------------------
// grid = 256 WGs x 1024 threads; WG g: layer l = g>>6, rows [32*(g&63), +32).
// Pipelined: at step s, layer l computes t = s - l. One barrier per step.
// h state: double-buffered hbuf[2][NLAY][HID] in d_ws, device-scope atomics.
__global__ __launch_bounds__(BLK, 4) void rnn_scan(
    const float* __restrict__ Wh,   // [NLAY][HID][HID]
    const float* __restrict__ Whh,  // [NLAY-1][HID][HID]
    const float* __restrict__ Bh,   // [NLAY][HID]
    const float* __restrict__ xin,  // [S_LEN][HID]
    float* hbuf,                    // [2][NLAY][HID] (zero-initialized)
    float* H3,                      // [S_LEN][HID]
    float* hfin,                    // [NLAY][HID] (into d_out)
    unsigned int* counter)
{
    __shared__ float sh_h[HID];   // h_l(t-1)
    __shared__ float sh_g[HID];   // h_{l-1}(t)

    const int g     = blockIdx.x;
    const int l     = g >> 6;
    const int slice = g & 63;
    const int r0    = slice * ROWS_PER_WG;
    const int tid   = threadIdx.x;
    const int wave  = tid >> 6;   // 0..15
    const int lane  = tid & 63;

    const float* myWh  = Wh + (size_t)l * HID * HID;
    const float* myWhh = (l > 0) ? (Whh + (size_t)(l - 1) * HID * HID) : nullptr;

    for (int s = 0; s < STEPS; ++s) {
        const int t  = s - l;
        const int rb = s & 1;
        const float* hread = hbuf + (size_t)rb * (NLAY * HID);
        float* hwrite      = hbuf + (size_t)(1 - rb) * (NLAY * HID);

        if (t >= 0 && t < S_LEN) {
            // stage input vectors into LDS (device-scope coherent loads)
            for (int i = tid; i < HID; i += BLK) {
                sh_h[i] = __hip_atomic_load(&hread[l * HID + i],
                                            __ATOMIC_RELAXED, __HIP_MEMORY_SCOPE_AGENT);
            }
            if (l > 0) {
                for (int i = tid; i < HID; i += BLK) {
                    sh_g[i] = __hip_atomic_load(&hread[(l - 1) * HID + i],
                                                __ATOMIC_RELAXED, __HIP_MEMORY_SCOPE_AGENT);
                }
            }
            __syncthreads();

            // each wave computes 2 output rows (streamed weights, coalesced f4)
            #pragma unroll
            for (int rr = 0; rr < 2; ++rr) {
                const int r = r0 + wave * 2 + rr;
                const float* wrow = myWh + (size_t)r * HID;
                float acc = 0.f;
                #pragma unroll
                for (int i = 0; i < 8; ++i) {
                    const int c = (lane + 64 * i) * 4;
                    const float4 wv = *(const float4*)(wrow + c);
                    const float4 hv = *(const float4*)(&sh_h[c]);
                    acc += wv.x * hv.x + wv.y * hv.y + wv.z * hv.z + wv.w * hv.w;
                }
                if (l > 0) {
                    const float* wrow2 = myWhh + (size_t)r * HID;
                    #pragma unroll
                    for (int i = 0; i < 8; ++i) {
                        const int c = (lane + 64 * i) * 4;
                        const float4 wv = *(const float4*)(wrow2 + c);
                        const float4 hv = *(const float4*)(&sh_g[c]);
                        acc += wv.x * hv.x + wv.y * hv.y + wv.z * hv.z + wv.w * hv.w;
                    }
                }
                // wave-wide sum
                #pragma unroll
                for (int off = 32; off > 0; off >>= 1)
                    acc += __shfl_down(acc, off, 64);
                if (lane == 0) {
                    float v = acc + Bh[l * HID + r];
                    if (l == 0) v += xin[(size_t)t * HID + r];
                    v = tanhf(v);
                    __hip_atomic_store(&hwrite[l * HID + r], v,
                                       __ATOMIC_RELAXED, __HIP_MEMORY_SCOPE_AGENT);
                    if (l == NLAY - 1) H3[(size_t)t * HID + r] = v;
                    if (t == S_LEN - 1) hfin[l * HID + r] = v;
                }
            }
            __syncthreads();
        }
        grid_barrier(counter, (unsigned int)NWG * (unsigned int)(s + 1));
    }
}

// ---------------- kernels 1 & 3: tiled fp32 NT-GEMM ------------------------
// C[M][N] = A[M][K] @ B[N][K]^T (+ bias[N]).  64x64 tile, BK=32, 256 thr,
// 4x4 per thread. M,N mult of 64; K mult of 32.
__global__ __launch_bounds__(256) void gemm_nt(
    const float* __restrict__ A, const float* __restrict__ B,
    const float* __restrict__ bias, float* __restrict__ C,
    int M, int N, int K)
{
    __shared__ float As[32][65];  // [k][m], padded
    __shared__ float Bs[32][65];  // [k][n]

    const int tid = threadIdx.x;
    const int tx = tid & 15, ty = tid >> 4;
    const int i0 = blockIdx.y * 64;
    const int j0 = blockIdx.x * 64;

    float acc[4][4] = {};

    for (int k0 = 0; k0 < K; k0 += 32) {
        #pragma unroll
        for (int ld = tid; ld < 64 * 32; ld += 256) {
            const int r = ld >> 5;
            const int k = ld & 31;
            As[k][r] = A[(size_t)(i0 + r) * K + k0 + k];
            Bs[k][r] = B[(size_t)(j0 + r) * K + k0 + k];
        }
        __syncthreads();
        #pragma unroll
        for (int kk = 0; kk < 32; ++kk) {
            float a[4], b[4];
            #pragma unroll
            for (int u = 0; u < 4; ++u) a[u] = As[kk][ty * 4 + u];
            #pragma unroll
            for (int v = 0; v < 4; ++v) b[v] = Bs[kk][tx * 4 + v];
            #pragma unroll
            for (int u = 0; u < 4; ++u)
                #pragma unroll
                for (int v = 0; v < 4; ++v)
                    acc[u][v] += a[u] * b[v];
        }
        __syncthreads();
    }
    #pragma unroll
    for (int u = 0; u < 4; ++u) {
        #pragma unroll
        for (int v = 0; v < 4; ++v) {
            const int i = i0 + ty * 4 + u;
            const int j = j0 + tx * 4 + v;
            float r = acc[u][v];
            if (bias) r += bias[j];
            C[(size_t)i * N + j] = r;
        }
    }
}

// ---------------- launch ---------------------------------------------------
extern "C" void kernel_launch(void* const* d_in, const int* in_sizes, int n_in,
                              void* d_out, int out_size, void* d_ws, size_t ws_size,
                              hipStream_t stream) {
    const float* x   = (const float*)d_in[0];  // [S][IN]
    const float* Wh  = (const float*)d_in[1];  // [L][H][H]
    const float* Whh = (const float*)d_in[2];  // [L-1][H][H]
    const float* Wx  = (const float*)d_in[3];  // [H][IN]
    const float* Wy  = (const float*)d_in[4];  // [IN][H]
    const float* Bh  = (const float*)d_in[5];  // [L][H]
    const float* By  = (const float*)d_in[6];  // [IN]

    float* out  = (float*)d_out;               // [S*IN | L*H]
    float* hfin = out + (size_t)S_LEN * IN_SZ;

    // workspace layout (floats): [64 counter area][2*L*H hbuf][S*H xin][S*H H3]
    float* wsf         = (float*)d_ws;
    unsigned int* ctr  = (unsigned int*)d_ws;
    float* hbuf        = wsf + 64;
    float* xin         = hbuf + 2 * NLAY * HID;
    float* H3          = xin + (size_t)S_LEN * HID;

    // zero counter + hbuf (ws is poisoned before every timed call)
    hipMemsetAsync(d_ws, 0, (64 + 2 * NLAY * HID) * sizeof(float), stream);

    // kernel 1: xin = x @ Wx^T   (M=S, N=H, K=IN)
    {
        dim3 grid(HID / 64, S_LEN / 64);
        gemm_nt<<<grid, 256, 0, stream>>>(x, Wx, nullptr, xin, S_LEN, HID, IN_SZ);
    }

    // kernel 2: the sequential scan (persistent, 1 WG per CU)
    rnn_scan<<<NWG, BLK, 0, stream>>>(Wh, Whh, Bh, xin, hbuf, H3, hfin, ctr);

    // kernel 3: ys = H3 @ Wy^T + By   (M=S, N=IN, K=H) -> d_out
    {
        dim3 grid(IN_SZ / 64, S_LEN / 64);
        gemm_nt<<<grid, 256, 0, stream>>>(H3, Wy, By, out, S_LEN, IN_SZ, HID);
    }
}

// Round 2
// 81544.476 us; speedup vs baseline: 1.2631x; 1.2631x over previous
//
#include <hip/hip_runtime.h>
#include <math.h>

// ---------------------------------------------------------------------------
// RNNv2 round 2: register-persistent fp16 weights + flag-based dataflow.
//   - 256 WGs x 1024 thr; WG g -> layer l=g>>6, wg-in-layer w=g&63.
//   - Each wave owns 2 output rows; weights (Wh row | Whh row / Wx row) live
//     in 48-64 packed-half2 VGPRs per lane for the whole kernel.
//   - h history hist[l][t][H/2] (packed half2, 32 MB ws) is write-once; per-
//     layer done-flags replace the global barrier (no 256-way atomic convoy).
//   - x @ Wx^T folded into layer 0 (GEMM1 deleted); output GEMM reads fp16
//     hist[3] directly.
// d_out = [ys (S*IN) | h_final (L*H)]
// ---------------------------------------------------------------------------

typedef unsigned int uint32;
typedef _Float16 half2_t __attribute__((ext_vector_type(2)));

#define S_LEN 2048
#define IN_SZ 1024
#define HID   2048
#define NLAY  4
#define NWG   256
#define BLK   1024
#define H2    1024   // uints per packed h vector (HID/2)

__device__ __forceinline__ float dot2(uint32 a, uint32 b, float c) {
    return __builtin_amdgcn_fdot2(__builtin_bit_cast(half2_t, a),
                                  __builtin_bit_cast(half2_t, b), c, false);
}
__device__ __forceinline__ uint32 packh2(float x, float y) {
    half2_t h; h.x = (_Float16)x; h.y = (_Float16)y;   // RNE converts
    return __builtin_bit_cast(uint32, h);
}

__global__ __launch_bounds__(BLK, 4) void rnn_scan(
    const float* __restrict__ Wh,   // [4][H][H]
    const float* __restrict__ Whh,  // [3][H][H]
    const float* __restrict__ Wx,   // [H][IN]
    const float* __restrict__ x,    // [S][IN]
    const float* __restrict__ Bh,   // [4][H]
    float* __restrict__ hfin,       // [4][H] (tail of d_out)
    uint32* hist,                   // [4][S][H2] packed half2
    uint32* flags)                  // [4][64]
{
    const int g   = blockIdx.x;
    const int l   = g >> 6;        // layer 0..3 (wave-uniform)
    const int w   = g & 63;        // wg within layer
    const int tid = threadIdx.x;
    const int v   = tid >> 6;      // wave 0..15
    const int k   = tid & 63;      // lane
    const int r0  = w * 32 + v * 2;  // first of this wave's 2 rows

    // ---- one-time: load + pack weights into registers --------------------
    // l==0 : wreg[rr*24 + 0..15] = Wh[0][r] cols, [16..23] = Wx[r] cols
    // l>=1 : wreg[rr*32 + 0..15] = Wh[l][r],      [16..31] = Whh[l-1][r]
    uint32 wreg[64];
    const float bh0 = Bh[l * HID + r0];
    const float bh1 = Bh[l * HID + r0 + 1];

    if (l == 0) {
        #pragma unroll
        for (int rr = 0; rr < 2; ++rr) {
            const float* wr = Wh + (size_t)(r0 + rr) * HID;
            #pragma unroll
            for (int j = 0; j < 16; ++j) {
                float2 f = *(const float2*)(wr + 2 * (k + 64 * j));
                wreg[rr * 24 + j] = packh2(f.x, f.y);
            }
            const float* xr = Wx + (size_t)(r0 + rr) * IN_SZ;
            #pragma unroll
            for (int j = 0; j < 8; ++j) {
                float2 f = *(const float2*)(xr + 2 * (k + 64 * j));
                wreg[rr * 24 + 16 + j] = packh2(f.x, f.y);
            }
        }
    } else {
        #pragma unroll
        for (int rr = 0; rr < 2; ++rr) {
            const float* wr  = Wh  + ((size_t)l * HID + r0 + rr) * HID;
            const float* wr2 = Whh + ((size_t)(l - 1) * HID + r0 + rr) * HID;
            #pragma unroll
            for (int j = 0; j < 16; ++j) {
                float2 f = *(const float2*)(wr + 2 * (k + 64 * j));
                wreg[rr * 32 + j] = packh2(f.x, f.y);
                float2 q = *(const float2*)(wr2 + 2 * (k + 64 * j));
                wreg[rr * 32 + 16 + j] = packh2(q.x, q.y);
            }
        }
    }

    uint32* histL = hist + (size_t)l * S_LEN * H2;
    uint32* histP = hist + (size_t)(l - 1) * S_LEN * H2;  // used only if l>0
    uint32* flagL = flags + l * 64;
    uint32* flagP = flags + (l - 1) * 64;

    // ---- timestep loop ----------------------------------------------------
    for (int t = 0; t < S_LEN; ++t) {
        const bool needOwn  = (t > 0);   // need h_l(t-1): flags[l][*]  >= t
        const bool needPrev = (l > 0);   // need h_{l-1}(t): flags[l-1][*] >= t+1
        if (needOwn || needPrev) {
            const uint32 tgtO = (uint32)t, tgtP = (uint32)(t + 1);
            for (;;) {
                int ok = 1;
                if (needOwn)
                    ok &= (__hip_atomic_load(&flagL[k], __ATOMIC_RELAXED,
                                             __HIP_MEMORY_SCOPE_AGENT) >= tgtO);
                if (needPrev)
                    ok &= (__hip_atomic_load(&flagP[k], __ATOMIC_RELAXED,
                                             __HIP_MEMORY_SCOPE_AGENT) >= tgtP);
                if (__all(ok)) break;
                __builtin_amdgcn_s_sleep(1);
            }
            // acquire: order the hist loads below after the observed flags
            (void)__hip_atomic_load(&flagL[0], __ATOMIC_ACQUIRE,
                                    __HIP_MEMORY_SCOPE_AGENT);
        }

        float acc0 = 0.f, acc1 = 0.f;

        if (needOwn) {  // Wh[l] . h_l(t-1)   (h_l(-1)=0 -> skip at t=0)
            uint32 hown[16];
            uint32* hp = histL + (size_t)(t - 1) * H2 + k;
            #pragma unroll
            for (int j = 0; j < 16; ++j)
                hown[j] = __hip_atomic_load(&hp[64 * j], __ATOMIC_RELAXED,
                                            __HIP_MEMORY_SCOPE_AGENT);
            if (l == 0) {
                #pragma unroll
                for (int j = 0; j < 16; ++j) {
                    acc0 = dot2(wreg[j],      hown[j], acc0);
                    acc1 = dot2(wreg[24 + j], hown[j], acc1);
                }
            } else {
                #pragma unroll
                for (int j = 0; j < 16; ++j) {
                    acc0 = dot2(wreg[j],      hown[j], acc0);
                    acc1 = dot2(wreg[32 + j], hown[j], acc1);
                }
            }
        }

        if (l == 0) {   // + Wx . x[t]  (x is static input: plain cached loads)
            const float* xr = x + (size_t)t * IN_SZ + 2 * k;
            #pragma unroll
            for (int j = 0; j < 8; ++j) {
                float2 f = *(const float2*)(xr + 128 * j);
                uint32 xp = packh2(f.x, f.y);
                acc0 = dot2(wreg[16 + j], xp, acc0);
                acc1 = dot2(wreg[40 + j], xp, acc1);
            }
        } else {        // + Whh[l-1] . h_{l-1}(t)
            uint32 hprev[16];
            uint32* gp = histP + (size_t)t * H2 + k;
            #pragma unroll
            for (int j = 0; j < 16; ++j)
                hprev[j] = __hip_atomic_load(&gp[64 * j], __ATOMIC_RELAXED,
                                            __HIP_MEMORY_SCOPE_AGENT);
            #pragma unroll
            for (int j = 0; j < 16; ++j) {
                acc0 = dot2(wreg[16 + j], hprev[j], acc0);
                acc1 = dot2(wreg[48 + j], hprev[j], acc1);
            }
        }

        // wave-wide butterfly reduce (both rows)
        #pragma unroll
        for (int off = 32; off > 0; off >>= 1) {
            acc0 += __shfl_xor(acc0, off, 64);
            acc1 += __shfl_xor(acc1, off, 64);
        }

        if (k == 0) {
            float h0 = tanhf(acc0 + bh0);
            float h1 = tanhf(acc1 + bh1);
            __hip_atomic_store(&histL[(size_t)t * H2 + (r0 >> 1)], packh2(h0, h1),
                               __ATOMIC_RELAXED, __HIP_MEMORY_SCOPE_AGENT);
            if (t == S_LEN - 1) {
                hfin[l * HID + r0]     = h0;
                hfin[l * HID + r0 + 1] = h1;
            }
        }
        __syncthreads();   // drains each wave's vmcnt before flag release
        if (tid == 0)
            __hip_atomic_store(&flagL[w], (uint32)(t + 1), __ATOMIC_RELEASE,
                               __HIP_MEMORY_SCOPE_AGENT);
    }
}

// ---------------------------------------------------------------------------
// Output GEMM: ys[t][j] = sum_k h3[t][k] * Wy[j][k] + By[j]
// A = hist[3] packed half2 [2048][1024u], B = Wy fp32 [1024][2048].
// ---------------------------------------------------------------------------
__global__ __launch_bounds__(256) void gemm_out(
    const uint32* __restrict__ A2, const float* __restrict__ B,
    const float* __restrict__ bias, float* __restrict__ C)
{
    __shared__ float As[32][65];
    __shared__ float Bs[32][65];

    const int tid = threadIdx.x;
    const int tx = tid & 15, ty = tid >> 4;
    const int i0 = blockIdx.y * 64;   // over M = S_LEN
    const int j0 = blockIdx.x * 64;   // over N = IN_SZ

    float acc[4][4] = {};

    for (int k0 = 0; k0 < HID; k0 += 32) {
        #pragma unroll
        for (int ld = tid; ld < 1024; ld += 256) {   // A: 64 rows x 16 uints
            const int r = ld >> 4, kk2 = ld & 15;
            half2_t h = __builtin_bit_cast(half2_t,
                A2[(size_t)(i0 + r) * H2 + (k0 >> 1) + kk2]);
            As[2 * kk2][r]     = (float)h.x;
            As[2 * kk2 + 1][r] = (float)h.y;
        }
        #pragma unroll
        for (int ld = tid; ld < 2048; ld += 256) {   // B: 64 rows x 32 k
            const int rn = ld >> 5, kk = ld & 31;
            Bs[kk][rn] = B[(size_t)(j0 + rn) * HID + k0 + kk];
        }
        __syncthreads();
        #pragma unroll
        for (int kk = 0; kk < 32; ++kk) {
            float a[4], b[4];
            #pragma unroll
            for (int u = 0; u < 4; ++u) a[u] = As[kk][ty * 4 + u];
            #pragma unroll
            for (int u = 0; u < 4; ++u) b[u] = Bs[kk][tx * 4 + u];
            #pragma unroll
            for (int u = 0; u < 4; ++u)
                #pragma unroll
                for (int q = 0; q < 4; ++q)
                    acc[u][q] += a[u] * b[q];
        }
        __syncthreads();
    }
    #pragma unroll
    for (int u = 0; u < 4; ++u)
        #pragma unroll
        for (int q = 0; q < 4; ++q) {
            const int i = i0 + ty * 4 + u;
            const int j = j0 + tx * 4 + q;
            C[(size_t)i * IN_SZ + j] = acc[u][q] + bias[j];
        }
}

// ---------------------------------------------------------------------------
extern "C" void kernel_launch(void* const* d_in, const int* in_sizes, int n_in,
                              void* d_out, int out_size, void* d_ws, size_t ws_size,
                              hipStream_t stream) {
    const float* x   = (const float*)d_in[0];
    const float* Wh  = (const float*)d_in[1];
    const float* Whh = (const float*)d_in[2];
    const float* Wx  = (const float*)d_in[3];
    const float* Wy  = (const float*)d_in[4];
    const float* Bh  = (const float*)d_in[5];
    const float* By  = (const float*)d_in[6];

    float* out  = (float*)d_out;
    float* hfin = out + (size_t)S_LEN * IN_SZ;

    // ws: [flags 4*64 u32, padded to 1024 u32][hist 4*2048*1024 u32 = 32 MB]
    uint32* flags = (uint32*)d_ws;
    uint32* hist  = (uint32*)d_ws + 1024;

    hipMemsetAsync(d_ws, 0, 1024 * sizeof(uint32), stream);  // zero flags

    rnn_scan<<<NWG, BLK, 0, stream>>>(Wh, Whh, Wx, x, Bh, hfin, hist, flags);

    gemm_out<<<dim3(IN_SZ / 64, S_LEN / 64), 256, 0, stream>>>(
        hist + (size_t)3 * S_LEN * H2, Wy, By, out);
}

// Round 3
// 42642.337 us; speedup vs baseline: 2.4154x; 1.9123x over previous
//
#include <hip/hip_runtime.h>
#include <math.h>

// ---------------------------------------------------------------------------
// RNNv2 round 3: register-persistent fp16 weights + flag dataflow,
//                single-poller-per-WG (kills the 4096-wave flag convoy),
//                64-bit coherent hist loads (dwordx2 sc1).
//   - 256 WGs x 1024 thr; WG g -> layer l=g>>6, wg-in-layer w=g&63.
//   - Each wave owns 2 output rows; weights live in 48-64 packed-half2 VGPRs.
//   - hist[l][t][H/2] packed half2 (32 MB ws), write-once; per-layer per-WG
//     done-flags; only wave 0 of each WG polls, rest wait at __syncthreads.
// d_out = [ys (S*IN) | h_final (L*H)]
// ---------------------------------------------------------------------------

typedef unsigned int uint32;
typedef unsigned long long uint64;
typedef _Float16 half2_t __attribute__((ext_vector_type(2)));

#define S_LEN 2048
#define IN_SZ 1024
#define HID   2048
#define NLAY  4
#define NWG   256
#define BLK   1024
#define H2    1024   // uints per packed h vector (HID/2)
#define H64   512    // ulongs per packed h vector

__device__ __forceinline__ float dot2(uint32 a, uint32 b, float c) {
    return __builtin_amdgcn_fdot2(__builtin_bit_cast(half2_t, a),
                                  __builtin_bit_cast(half2_t, b), c, false);
}
__device__ __forceinline__ uint32 packh2(float x, float y) {
    half2_t h; h.x = (_Float16)x; h.y = (_Float16)y;   // RNE converts
    return __builtin_bit_cast(uint32, h);
}

__global__ __launch_bounds__(BLK, 4) void rnn_scan(
    const float* __restrict__ Wh,   // [4][H][H]
    const float* __restrict__ Whh,  // [3][H][H]
    const float* __restrict__ Wx,   // [H][IN]
    const float* __restrict__ x,    // [S][IN]
    const float* __restrict__ Bh,   // [4][H]
    float* __restrict__ hfin,       // [4][H] (tail of d_out)
    uint32* hist,                   // [4][S][H2] packed half2
    uint32* flags)                  // [4][64]
{
    const int g   = blockIdx.x;
    const int l   = g >> 6;          // layer 0..3 (wave-uniform)
    const int w   = g & 63;          // wg within layer
    const int tid = threadIdx.x;
    const int v   = tid >> 6;        // wave 0..15
    const int k   = tid & 63;        // lane
    const int r0  = w * 32 + v * 2;  // first of this wave's 2 rows

    // ---- one-time: load + pack weights into registers --------------------
    // Column order matches 64-bit hist loads: ulong u = k + 64*j' holds
    // h columns 4u..4u+3; weight regs [2j'] = cols(4u,4u+1), [2j'+1] = (4u+2,4u+3).
    // l==0 : wreg[rr*24 + 0..15] = Wh[0][r], [16..23] = Wx[r]
    // l>=1 : wreg[rr*32 + 0..15] = Wh[l][r], [16..31] = Whh[l-1][r]
    uint32 wreg[64];
    const float bh0 = Bh[l * HID + r0];
    const float bh1 = Bh[l * HID + r0 + 1];

    if (l == 0) {
        #pragma unroll
        for (int rr = 0; rr < 2; ++rr) {
            const float* wr = Wh + (size_t)(r0 + rr) * HID;
            #pragma unroll
            for (int j = 0; j < 8; ++j) {
                float4 f = *(const float4*)(wr + 4 * (k + 64 * j));
                wreg[rr * 24 + 2 * j]     = packh2(f.x, f.y);
                wreg[rr * 24 + 2 * j + 1] = packh2(f.z, f.w);
            }
            const float* xr = Wx + (size_t)(r0 + rr) * IN_SZ;
            #pragma unroll
            for (int j = 0; j < 4; ++j) {
                float4 f = *(const float4*)(xr + 4 * (k + 64 * j));
                wreg[rr * 24 + 16 + 2 * j]     = packh2(f.x, f.y);
                wreg[rr * 24 + 16 + 2 * j + 1] = packh2(f.z, f.w);
            }
        }
    } else {
        #pragma unroll
        for (int rr = 0; rr < 2; ++rr) {
            const float* wr  = Wh  + ((size_t)l * HID + r0 + rr) * HID;
            const float* wr2 = Whh + ((size_t)(l - 1) * HID + r0 + rr) * HID;
            #pragma unroll
            for (int j = 0; j < 8; ++j) {
                float4 f = *(const float4*)(wr + 4 * (k + 64 * j));
                wreg[rr * 32 + 2 * j]     = packh2(f.x, f.y);
                wreg[rr * 32 + 2 * j + 1] = packh2(f.z, f.w);
                float4 q = *(const float4*)(wr2 + 4 * (k + 64 * j));
                wreg[rr * 32 + 16 + 2 * j]     = packh2(q.x, q.y);
                wreg[rr * 32 + 16 + 2 * j + 1] = packh2(q.z, q.w);
            }
        }
    }

    uint32* histL = hist + (size_t)l * S_LEN * H2;
    uint32* histP = hist + (size_t)(l - 1) * S_LEN * H2;  // only if l>0
    uint32* flagL = flags + l * 64;
    uint32* flagP = flags + (l - 1) * 64;

    // ---- timestep loop ----------------------------------------------------
    for (int t = 0; t < S_LEN; ++t) {
        const bool needOwn  = (t > 0);   // h_l(t-1):   flags[l][*]   >= t
        const bool needPrev = (l > 0);   // h_{l-1}(t): flags[l-1][*] >= t+1

        // only wave 0 polls; other 15 waves wait at the barrier
        if (v == 0 && (needOwn || needPrev)) {
            const uint32 tgtO = (uint32)t, tgtP = (uint32)(t + 1);
            for (;;) {
                int ok = 1;
                if (needOwn)
                    ok &= (__hip_atomic_load(&flagL[k], __ATOMIC_RELAXED,
                                             __HIP_MEMORY_SCOPE_AGENT) >= tgtO);
                if (needPrev)
                    ok &= (__hip_atomic_load(&flagP[k], __ATOMIC_RELAXED,
                                             __HIP_MEMORY_SCOPE_AGENT) >= tgtP);
                if (__all(ok)) break;
                __builtin_amdgcn_s_sleep(1);
            }
            // acquire: order subsequent hist loads after observed flags
            (void)__hip_atomic_load(&flagL[0], __ATOMIC_ACQUIRE,
                                    __HIP_MEMORY_SCOPE_AGENT);
        }
        if (needOwn || needPrev) __syncthreads();

        float acc0 = 0.f, acc1 = 0.f;

        if (needOwn) {  // Wh[l] . h_l(t-1)
            const uint64* h64 = (const uint64*)(histL + (size_t)(t - 1) * H2);
            uint64 hw[8];
            #pragma unroll
            for (int j = 0; j < 8; ++j)
                hw[j] = __hip_atomic_load(&h64[k + 64 * j], __ATOMIC_RELAXED,
                                          __HIP_MEMORY_SCOPE_AGENT);
            const int b1 = (l == 0) ? 24 : 32;
            #pragma unroll
            for (int j = 0; j < 8; ++j) {
                const uint32 lo = (uint32)hw[j], hi = (uint32)(hw[j] >> 32);
                acc0 = dot2(wreg[2 * j],          lo, acc0);
                acc0 = dot2(wreg[2 * j + 1],      hi, acc0);
                acc1 = dot2(wreg[b1 + 2 * j],     lo, acc1);
                acc1 = dot2(wreg[b1 + 2 * j + 1], hi, acc1);
            }
        }

        if (l == 0) {   // + Wx . x[t]  (static input, plain cached loads)
            const float* xr = x + (size_t)t * IN_SZ;
            #pragma unroll
            for (int j = 0; j < 4; ++j) {
                float4 f = *(const float4*)(xr + 4 * (k + 64 * j));
                const uint32 lo = packh2(f.x, f.y), hi = packh2(f.z, f.w);
                acc0 = dot2(wreg[16 + 2 * j],     lo, acc0);
                acc0 = dot2(wreg[16 + 2 * j + 1], hi, acc0);
                acc1 = dot2(wreg[40 + 2 * j],     lo, acc1);
                acc1 = dot2(wreg[40 + 2 * j + 1], hi, acc1);
            }
        } else {        // + Whh[l-1] . h_{l-1}(t)
            const uint64* g64 = (const uint64*)(histP + (size_t)t * H2);
            uint64 gw[8];
            #pragma unroll
            for (int j = 0; j < 8; ++j)
                gw[j] = __hip_atomic_load(&g64[k + 64 * j], __ATOMIC_RELAXED,
                                          __HIP_MEMORY_SCOPE_AGENT);
            #pragma unroll
            for (int j = 0; j < 8; ++j) {
                const uint32 lo = (uint32)gw[j], hi = (uint32)(gw[j] >> 32);
                acc0 = dot2(wreg[16 + 2 * j],     lo, acc0);
                acc0 = dot2(wreg[16 + 2 * j + 1], hi, acc0);
                acc1 = dot2(wreg[48 + 2 * j],     lo, acc1);
                acc1 = dot2(wreg[48 + 2 * j + 1], hi, acc1);
            }
        }

        // wave-wide butterfly reduce (both rows)
        #pragma unroll
        for (int off = 32; off > 0; off >>= 1) {
            acc0 += __shfl_xor(acc0, off, 64);
            acc1 += __shfl_xor(acc1, off, 64);
        }

        if (k == 0) {
            float h0 = tanhf(acc0 + bh0);
            float h1 = tanhf(acc1 + bh1);
            __hip_atomic_store(&histL[(size_t)t * H2 + (r0 >> 1)], packh2(h0, h1),
                               __ATOMIC_RELAXED, __HIP_MEMORY_SCOPE_AGENT);
            if (t == S_LEN - 1) {
                hfin[l * HID + r0]     = h0;
                hfin[l * HID + r0 + 1] = h1;
            }
        }
        __syncthreads();   // all waves' h-stores issued & drained
        if (tid == 0)
            __hip_atomic_store(&flagL[w], (uint32)(t + 1), __ATOMIC_RELEASE,
                               __HIP_MEMORY_SCOPE_AGENT);
    }
}

// ---------------------------------------------------------------------------
// Output GEMM: ys[t][j] = sum_k h3[t][k] * Wy[j][k] + By[j]
// A = hist[3] packed half2 [2048][1024u], B = Wy fp32 [1024][2048].
// ---------------------------------------------------------------------------
__global__ __launch_bounds__(256) void gemm_out(
    const uint32* __restrict__ A2, const float* __restrict__ B,
    const float* __restrict__ bias, float* __restrict__ C)
{
    __shared__ float As[32][65];
    __shared__ float Bs[32][65];

    const int tid = threadIdx.x;
    const int tx = tid & 15, ty = tid >> 4;
    const int i0 = blockIdx.y * 64;   // over M = S_LEN
    const int j0 = blockIdx.x * 64;   // over N = IN_SZ

    float acc[4][4] = {};

    for (int k0 = 0; k0 < HID; k0 += 32) {
        #pragma unroll
        for (int ld = tid; ld < 1024; ld += 256) {   // A: 64 rows x 16 uints
            const int r = ld >> 4, kk2 = ld & 15;
            half2_t h = __builtin_bit_cast(half2_t,
                A2[(size_t)(i0 + r) * H2 + (k0 >> 1) + kk2]);
            As[2 * kk2][r]     = (float)h.x;
            As[2 * kk2 + 1][r] = (float)h.y;
        }
        #pragma unroll
        for (int ld = tid; ld < 2048; ld += 256) {   // B: 64 rows x 32 k
            const int rn = ld >> 5, kk = ld & 31;
            Bs[kk][rn] = B[(size_t)(j0 + rn) * HID + k0 + kk];
        }
        __syncthreads();
        #pragma unroll
        for (int kk = 0; kk < 32; ++kk) {
            float a[4], b[4];
            #pragma unroll
            for (int u = 0; u < 4; ++u) a[u] = As[kk][ty * 4 + u];
            #pragma unroll
            for (int u = 0; u < 4; ++u) b[u] = Bs[kk][tx * 4 + u];
            #pragma unroll
            for (int u = 0; u < 4; ++u)
                #pragma unroll
                for (int q = 0; q < 4; ++q)
                    acc[u][q] += a[u] * b[q];
        }
        __syncthreads();
    }
    #pragma unroll
    for (int u = 0; u < 4; ++u)
        #pragma unroll
        for (int q = 0; q < 4; ++q) {
            const int i = i0 + ty * 4 + u;
            const int j = j0 + tx * 4 + q;
            C[(size_t)i * IN_SZ + j] = acc[u][q] + bias[j];
        }
}

// ---------------------------------------------------------------------------
extern "C" void kernel_launch(void* const* d_in, const int* in_sizes, int n_in,
                              void* d_out, int out_size, void* d_ws, size_t ws_size,
                              hipStream_t stream) {
    const float* x   = (const float*)d_in[0];
    const float* Wh  = (const float*)d_in[1];
    const float* Whh = (const float*)d_in[2];
    const float* Wx  = (const float*)d_in[3];
    const float* Wy  = (const float*)d_in[4];
    const float* Bh  = (const float*)d_in[5];
    const float* By  = (const float*)d_in[6];

    float* out  = (float*)d_out;
    float* hfin = out + (size_t)S_LEN * IN_SZ;

    // ws: [flags 4*64 u32, padded to 1024 u32][hist 4*2048*1024 u32 = 32 MB]
    uint32* flags = (uint32*)d_ws;
    uint32* hist  = (uint32*)d_ws + 1024;

    hipMemsetAsync(d_ws, 0, 1024 * sizeof(uint32), stream);  // zero flags

    rnn_scan<<<NWG, BLK, 0, stream>>>(Wh, Whh, Wx, x, Bh, hfin, hist, flags);

    gemm_out<<<dim3(IN_SZ / 64, S_LEN / 64), 256, 0, stream>>>(
        hist + (size_t)3 * S_LEN * H2, Wy, By, out);
}

// Round 4
// 17539.914 us; speedup vs baseline: 5.8722x; 2.4312x over previous
//
#include <hip/hip_runtime.h>
#include <math.h>

// ---------------------------------------------------------------------------
// RNNv2 round 4: register-persistent fp16 weights + flag dataflow
//                + LDS broadcast of h vectors (kills 16x L3 read amplification).
//   - 256 WGs x 1024 thr; WG g -> layer l=g>>6, wg-in-layer w=g&63.
//   - Each wave owns 2 output rows; weights live in 64 packed-half2 VGPRs,
//     packed in 8-cols-per-lane order so LDS reads are ds_read_b128.
//   - Per step: ONE cooperative global->LDS load of h_own/h_prev (8 KB),
//     then 16 waves consume from LDS.
// d_out = [ys (S*IN) | h_final (L*H)]
// ---------------------------------------------------------------------------

typedef unsigned int uint32;
typedef unsigned long long uint64;
typedef _Float16 half2_t __attribute__((ext_vector_type(2)));

#define S_LEN 2048
#define IN_SZ 1024
#define HID   2048
#define NLAY  4
#define NWG   256
#define BLK   1024
#define H2    1024   // uints per packed h vector (HID/2)

__device__ __forceinline__ float dot2(uint32 a, uint32 b, float c) {
    return __builtin_amdgcn_fdot2(__builtin_bit_cast(half2_t, a),
                                  __builtin_bit_cast(half2_t, b), c, false);
}
__device__ __forceinline__ uint32 packh2(float x, float y) {
    half2_t h; h.x = (_Float16)x; h.y = (_Float16)y;   // RNE converts
    return __builtin_bit_cast(uint32, h);
}

__global__ __launch_bounds__(BLK, 4) void rnn_scan(
    const float* __restrict__ Wh,   // [4][H][H]
    const float* __restrict__ Whh,  // [3][H][H]
    const float* __restrict__ Wx,   // [H][IN]
    const float* __restrict__ x,    // [S][IN]
    const float* __restrict__ Bh,   // [4][H]
    float* __restrict__ hfin,       // [4][H] (tail of d_out)
    uint32* hist,                   // [4][S][H2] packed half2
    uint32* flags)                  // [4][64]
{
    __shared__ __align__(16) uint32 sh_own[H2];   // h_l(t-1), packed half2
    __shared__ __align__(16) uint32 sh_prev[H2];  // h_{l-1}(t), packed half2

    const int g   = blockIdx.x;
    const int l   = g >> 6;          // layer 0..3 (wave-uniform)
    const int w   = g & 63;          // wg within layer
    const int tid = threadIdx.x;
    const int v   = tid >> 6;        // wave 0..15
    const int k   = tid & 63;        // lane
    const int r0  = w * 32 + v * 2;  // first of this wave's 2 rows

    // ---- one-time: load + pack weights into registers --------------------
    // Column mapping (matches uint4 LDS reads): for chunk j, lane k covers
    // columns 8k+512j .. 8k+512j+7  (4 packed-half2 regs per chunk).
    // wA[16*rr + 4j+q] = Wh row rr;  wB = Whh rows (l>=1) or Wx rows (l==0).
    uint32 wA[32], wB[32];
    const float bh0 = Bh[l * HID + r0];
    const float bh1 = Bh[l * HID + r0 + 1];

    #pragma unroll
    for (int rr = 0; rr < 2; ++rr) {
        const float* wr = Wh + ((size_t)l * HID + r0 + rr) * HID;
        #pragma unroll
        for (int j = 0; j < 4; ++j) {
            const float* p = wr + 8 * k + 512 * j;
            float4 f0 = *(const float4*)p;
            float4 f1 = *(const float4*)(p + 4);
            wA[16 * rr + 4 * j + 0] = packh2(f0.x, f0.y);
            wA[16 * rr + 4 * j + 1] = packh2(f0.z, f0.w);
            wA[16 * rr + 4 * j + 2] = packh2(f1.x, f1.y);
            wA[16 * rr + 4 * j + 3] = packh2(f1.z, f1.w);
        }
    }
    if (l == 0) {
        #pragma unroll
        for (int rr = 0; rr < 2; ++rr) {
            const float* xr = Wx + (size_t)(r0 + rr) * IN_SZ;
            #pragma unroll
            for (int j = 0; j < 2; ++j) {
                const float* p = xr + 8 * k + 512 * j;
                float4 f0 = *(const float4*)p;
                float4 f1 = *(const float4*)(p + 4);
                wB[8 * rr + 4 * j + 0] = packh2(f0.x, f0.y);
                wB[8 * rr + 4 * j + 1] = packh2(f0.z, f0.w);
                wB[8 * rr + 4 * j + 2] = packh2(f1.x, f1.y);
                wB[8 * rr + 4 * j + 3] = packh2(f1.z, f1.w);
            }
        }
    } else {
        #pragma unroll
        for (int rr = 0; rr < 2; ++rr) {
            const float* wr2 = Whh + ((size_t)(l - 1) * HID + r0 + rr) * HID;
            #pragma unroll
            for (int j = 0; j < 4; ++j) {
                const float* p = wr2 + 8 * k + 512 * j;
                float4 f0 = *(const float4*)p;
                float4 f1 = *(const float4*)(p + 4);
                wB[16 * rr + 4 * j + 0] = packh2(f0.x, f0.y);
                wB[16 * rr + 4 * j + 1] = packh2(f0.z, f0.w);
                wB[16 * rr + 4 * j + 2] = packh2(f1.x, f1.y);
                wB[16 * rr + 4 * j + 3] = packh2(f1.z, f1.w);
            }
        }
    }

    uint32* histL = hist + (size_t)l * S_LEN * H2;
    uint32* histP = hist + (size_t)(l - 1) * S_LEN * H2;  // only if l>0
    uint32* flagL = flags + l * 64;
    uint32* flagP = flags + (l - 1) * 64;

    // ---- timestep loop ----------------------------------------------------
    for (int t = 0; t < S_LEN; ++t) {
        const bool needOwn  = (t > 0);   // h_l(t-1):   flags[l][*]   >= t
        const bool needPrev = (l > 0);   // h_{l-1}(t): flags[l-1][*] >= t+1

        // only wave 0 polls; other 15 waves wait at barrier (1)
        if (v == 0 && (needOwn || needPrev)) {
            const uint32 tgtO = (uint32)t, tgtP = (uint32)(t + 1);
            for (;;) {
                int ok = 1;
                if (needOwn)
                    ok &= (__hip_atomic_load(&flagL[k], __ATOMIC_RELAXED,
                                             __HIP_MEMORY_SCOPE_AGENT) >= tgtO);
                if (needPrev)
                    ok &= (__hip_atomic_load(&flagP[k], __ATOMIC_RELAXED,
                                             __HIP_MEMORY_SCOPE_AGENT) >= tgtP);
                if (__all(ok)) break;
                __builtin_amdgcn_s_sleep(1);
            }
            (void)__hip_atomic_load(&flagL[0], __ATOMIC_ACQUIRE,
                                    __HIP_MEMORY_SCOPE_AGENT);
        }
        __syncthreads();   // (1) flags confirmed for the whole WG

        // ONE cooperative global->LDS broadcast load (8 KB)
        if (needOwn && tid < 512) {
            ((uint64*)sh_own)[tid] = __hip_atomic_load(
                (const uint64*)(histL + (size_t)(t - 1) * H2) + tid,
                __ATOMIC_RELAXED, __HIP_MEMORY_SCOPE_AGENT);
        }
        if (l > 0 && tid >= 512) {
            ((uint64*)sh_prev)[tid - 512] = __hip_atomic_load(
                (const uint64*)(histP + (size_t)t * H2) + (tid - 512),
                __ATOMIC_RELAXED, __HIP_MEMORY_SCOPE_AGENT);
        }
        __syncthreads();   // (2) LDS staged

        float acc0 = 0.f, acc1 = 0.f;

        if (needOwn) {  // Wh[l] . h_l(t-1)
            #pragma unroll
            for (int j = 0; j < 4; ++j) {
                uint4 hv = ((const uint4*)sh_own)[k + 64 * j];
                acc0 = dot2(wA[4 * j + 0], hv.x, acc0);
                acc0 = dot2(wA[4 * j + 1], hv.y, acc0);
                acc0 = dot2(wA[4 * j + 2], hv.z, acc0);
                acc0 = dot2(wA[4 * j + 3], hv.w, acc0);
                acc1 = dot2(wA[16 + 4 * j + 0], hv.x, acc1);
                acc1 = dot2(wA[16 + 4 * j + 1], hv.y, acc1);
                acc1 = dot2(wA[16 + 4 * j + 2], hv.z, acc1);
                acc1 = dot2(wA[16 + 4 * j + 3], hv.w, acc1);
            }
        }

        if (l == 0) {   // + Wx . x[t]  (static input, plain cached loads)
            #pragma unroll
            for (int j = 0; j < 2; ++j) {
                const float* p = x + (size_t)t * IN_SZ + 8 * k + 512 * j;
                float4 f0 = *(const float4*)p;
                float4 f1 = *(const float4*)(p + 4);
                const uint32 x0 = packh2(f0.x, f0.y), x1 = packh2(f0.z, f0.w);
                const uint32 x2 = packh2(f1.x, f1.y), x3 = packh2(f1.z, f1.w);
                acc0 = dot2(wB[4 * j + 0], x0, acc0);
                acc0 = dot2(wB[4 * j + 1], x1, acc0);
                acc0 = dot2(wB[4 * j + 2], x2, acc0);
                acc0 = dot2(wB[4 * j + 3], x3, acc0);
                acc1 = dot2(wB[8 + 4 * j + 0], x0, acc1);
                acc1 = dot2(wB[8 + 4 * j + 1], x1, acc1);
                acc1 = dot2(wB[8 + 4 * j + 2], x2, acc1);
                acc1 = dot2(wB[8 + 4 * j + 3], x3, acc1);
            }
        } else {        // + Whh[l-1] . h_{l-1}(t)
            #pragma unroll
            for (int j = 0; j < 4; ++j) {
                uint4 gv = ((const uint4*)sh_prev)[k + 64 * j];
                acc0 = dot2(wB[4 * j + 0], gv.x, acc0);
                acc0 = dot2(wB[4 * j + 1], gv.y, acc0);
                acc0 = dot2(wB[4 * j + 2], gv.z, acc0);
                acc0 = dot2(wB[4 * j + 3], gv.w, acc0);
                acc1 = dot2(wB[16 + 4 * j + 0], gv.x, acc1);
                acc1 = dot2(wB[16 + 4 * j + 1], gv.y, acc1);
                acc1 = dot2(wB[16 + 4 * j + 2], gv.z, acc1);
                acc1 = dot2(wB[16 + 4 * j + 3], gv.w, acc1);
            }
        }

        // wave-wide butterfly reduce (both rows)
        #pragma unroll
        for (int off = 32; off > 0; off >>= 1) {
            acc0 += __shfl_xor(acc0, off, 64);
            acc1 += __shfl_xor(acc1, off, 64);
        }

        if (k == 0) {
            float h0 = tanhf(acc0 + bh0);
            float h1 = tanhf(acc1 + bh1);
            __hip_atomic_store(&histL[(size_t)t * H2 + (r0 >> 1)], packh2(h0, h1),
                               __ATOMIC_RELAXED, __HIP_MEMORY_SCOPE_AGENT);
            if (t == S_LEN - 1) {
                hfin[l * HID + r0]     = h0;
                hfin[l * HID + r0 + 1] = h1;
            }
        }
        __syncthreads();   // (3) all waves' h-stores drained
        if (tid == 0)
            __hip_atomic_store(&flagL[w], (uint32)(t + 1), __ATOMIC_RELEASE,
                               __HIP_MEMORY_SCOPE_AGENT);
    }
}

// ---------------------------------------------------------------------------
// Output GEMM: ys[t][j] = sum_k h3[t][k] * Wy[j][k] + By[j]
// A = hist[3] packed half2 [2048][1024u], B = Wy fp32 [1024][2048].
// ---------------------------------------------------------------------------
__global__ __launch_bounds__(256) void gemm_out(
    const uint32* __restrict__ A2, const float* __restrict__ B,
    const float* __restrict__ bias, float* __restrict__ C)
{
    __shared__ float As[32][65];
    __shared__ float Bs[32][65];

    const int tid = threadIdx.x;
    const int tx = tid & 15, ty = tid >> 4;
    const int i0 = blockIdx.y * 64;   // over M = S_LEN
    const int j0 = blockIdx.x * 64;   // over N = IN_SZ

    float acc[4][4] = {};

    for (int k0 = 0; k0 < HID; k0 += 32) {
        #pragma unroll
        for (int ld = tid; ld < 1024; ld += 256) {   // A: 64 rows x 16 uints
            const int r = ld >> 4, kk2 = ld & 15;
            half2_t h = __builtin_bit_cast(half2_t,
                A2[(size_t)(i0 + r) * H2 + (k0 >> 1) + kk2]);
            As[2 * kk2][r]     = (float)h.x;
            As[2 * kk2 + 1][r] = (float)h.y;
        }
        #pragma unroll
        for (int ld = tid; ld < 2048; ld += 256) {   // B: 64 rows x 32 k
            const int rn = ld >> 5, kk = ld & 31;
            Bs[kk][rn] = B[(size_t)(j0 + rn) * HID + k0 + kk];
        }
        __syncthreads();
        #pragma unroll
        for (int kk = 0; kk < 32; ++kk) {
            float a[4], b[4];
            #pragma unroll
            for (int u = 0; u < 4; ++u) a[u] = As[kk][ty * 4 + u];
            #pragma unroll
            for (int u = 0; u < 4; ++u) b[u] = Bs[kk][tx * 4 + u];
            #pragma unroll
            for (int u = 0; u < 4; ++u)
                #pragma unroll
                for (int q = 0; q < 4; ++q)
                    acc[u][q] += a[u] * b[q];
        }
        __syncthreads();
    }
    #pragma unroll
    for (int u = 0; u < 4; ++u)
        #pragma unroll
        for (int q = 0; q < 4; ++q) {
            const int i = i0 + ty * 4 + u;
            const int j = j0 + tx * 4 + q;
            C[(size_t)i * IN_SZ + j] = acc[u][q] + bias[j];
        }
}

// ---------------------------------------------------------------------------
extern "C" void kernel_launch(void* const* d_in, const int* in_sizes, int n_in,
                              void* d_out, int out_size, void* d_ws, size_t ws_size,
                              hipStream_t stream) {
    const float* x   = (const float*)d_in[0];
    const float* Wh  = (const float*)d_in[1];
    const float* Whh = (const float*)d_in[2];
    const float* Wx  = (const float*)d_in[3];
    const float* Wy  = (const float*)d_in[4];
    const float* Bh  = (const float*)d_in[5];
    const float* By  = (const float*)d_in[6];

    float* out  = (float*)d_out;
    float* hfin = out + (size_t)S_LEN * IN_SZ;

    // ws: [flags 4*64 u32, padded to 1024 u32][hist 4*2048*1024 u32 = 32 MB]
    uint32* flags = (uint32*)d_ws;
    uint32* hist  = (uint32*)d_ws + 1024;

    hipMemsetAsync(d_ws, 0, 1024 * sizeof(uint32), stream);  // zero flags

    rnn_scan<<<NWG, BLK, 0, stream>>>(Wh, Whh, Wx, x, Bh, hfin, hist, flags);

    gemm_out<<<dim3(IN_SZ / 64, S_LEN / 64), 256, 0, stream>>>(
        hist + (size_t)3 * S_LEN * H2, Wy, By, out);
}

// Round 5
// 8998.640 us; speedup vs baseline: 11.4460x; 1.9492x over previous
//
#include <hip/hip_runtime.h>
#include <math.h>

// ---------------------------------------------------------------------------
// RNNv2 round 5: data-as-signal dataflow (no flags), sentinel-initialized
//                history, parity double-buffered LDS, one barrier per step,
//                xin = x@Wx^T hoisted to a pre-GEMM (layer-0 path halved).
//   - 256 WGs x 1024 thr; WG g -> layer l=g>>6, wg-in-layer w=g&63.
//   - Each wave owns 2 output rows; weights live in packed-half2 VGPRs/AGPRs.
//   - hist[l][t][H2] packed half2, pre-filled 0x7F7F7F7F (fp16 NaN pair).
//     A produced h word can never be NaN, so "word != sentinel" == ready.
//     Each thread polls exactly its own word -> ONE L3 round trip per step.
// d_out = [ys (S*IN) | h_final (L*H)]
// ---------------------------------------------------------------------------

typedef unsigned int uint32;
typedef unsigned long long uint64;
typedef _Float16 half2_t __attribute__((ext_vector_type(2)));

#define S_LEN 2048
#define IN_SZ 1024
#define HID   2048
#define NLAY  4
#define NWG   256
#define BLK   1024
#define H2    1024   // uints per packed h vector (HID/2)
#define SENT  0x7F7F7F7Fu

__device__ __forceinline__ float dot2(uint32 a, uint32 b, float c) {
    return __builtin_amdgcn_fdot2(__builtin_bit_cast(half2_t, a),
                                  __builtin_bit_cast(half2_t, b), c, false);
}
__device__ __forceinline__ uint32 packh2(float x, float y) {
    half2_t h; h.x = (_Float16)x; h.y = (_Float16)y;   // RNE converts
    return __builtin_bit_cast(uint32, h);
}

__global__ __launch_bounds__(BLK, 4) void rnn_scan(
    const float* __restrict__ Wh,   // [4][H][H]
    const float* __restrict__ Whh,  // [3][H][H]
    const float* __restrict__ xin,  // [S][H]  (x @ Wx^T, fp32)
    const float* __restrict__ Bh,   // [4][H]
    float* __restrict__ hfin,       // [4][H] (tail of d_out)
    uint32* hist)                   // [4][S][H2] packed half2, sentinel-filled
{
    __shared__ __align__(16) uint32 sh_own[2][H2];
    __shared__ __align__(16) uint32 sh_prev[2][H2];

    const int g   = blockIdx.x;
    const int l   = g >> 6;          // layer 0..3 (wave-uniform)
    const int w   = g & 63;          // wg within layer
    const int tid = threadIdx.x;
    const int v   = tid >> 6;        // wave 0..15
    const int k   = tid & 63;        // lane
    const int r0  = w * 32 + v * 2;  // first of this wave's 2 rows

    // ---- one-time: load + pack weights into registers --------------------
    // Chunk j (j=0..3): lane k covers columns 8k+512j .. +7, i.e. uint4 at
    // uint index 4k+256j of the packed h row. wA = Wh rows, wB = Whh rows.
    uint32 wA[32], wB[32];
    const float bh0 = Bh[l * HID + r0];
    const float bh1 = Bh[l * HID + r0 + 1];

    #pragma unroll
    for (int rr = 0; rr < 2; ++rr) {
        const float* wr = Wh + ((size_t)l * HID + r0 + rr) * HID;
        #pragma unroll
        for (int j = 0; j < 4; ++j) {
            const float* p = wr + 8 * k + 512 * j;
            float4 f0 = *(const float4*)p;
            float4 f1 = *(const float4*)(p + 4);
            wA[16 * rr + 4 * j + 0] = packh2(f0.x, f0.y);
            wA[16 * rr + 4 * j + 1] = packh2(f0.z, f0.w);
            wA[16 * rr + 4 * j + 2] = packh2(f1.x, f1.y);
            wA[16 * rr + 4 * j + 3] = packh2(f1.z, f1.w);
        }
    }
    if (l > 0) {
        #pragma unroll
        for (int rr = 0; rr < 2; ++rr) {
            const float* wr2 = Whh + ((size_t)(l - 1) * HID + r0 + rr) * HID;
            #pragma unroll
            for (int j = 0; j < 4; ++j) {
                const float* p = wr2 + 8 * k + 512 * j;
                float4 f0 = *(const float4*)p;
                float4 f1 = *(const float4*)(p + 4);
                wB[16 * rr + 4 * j + 0] = packh2(f0.x, f0.y);
                wB[16 * rr + 4 * j + 1] = packh2(f0.z, f0.w);
                wB[16 * rr + 4 * j + 2] = packh2(f1.x, f1.y);
                wB[16 * rr + 4 * j + 3] = packh2(f1.z, f1.w);
            }
        }
    }

    uint32* histL = hist + (size_t)l * S_LEN * H2;
    uint32* histP = hist + (size_t)(l - 1) * S_LEN * H2;  // only if l>0

    // ---- timestep loop ----------------------------------------------------
    for (int t = 0; t < S_LEN; ++t) {
        const int  par      = t & 1;
        const bool needOwn  = (t > 0);
        const bool needPrev = (l > 0);

        // layer 0: prefetch this wave's xin pair early (static data)
        float2 xv = make_float2(0.f, 0.f);
        if (l == 0) xv = *(const float2*)(xin + (size_t)t * HID + r0);

        // stage: each thread polls its OWN word(s) until non-sentinel
        {
            bool na = needOwn, nb = needPrev;
            const uint32* pOwn  = histL + (size_t)(t - 1) * H2 + tid;
            const uint32* pPrev = histP + (size_t)t * H2 + tid;
            while (na || nb) {
                if (na) {
                    uint32 a = __hip_atomic_load(pOwn, __ATOMIC_RELAXED,
                                                 __HIP_MEMORY_SCOPE_AGENT);
                    if (a != SENT) { sh_own[par][tid] = a; na = false; }
                }
                if (nb) {
                    uint32 b = __hip_atomic_load(pPrev, __ATOMIC_RELAXED,
                                                 __HIP_MEMORY_SCOPE_AGENT);
                    if (b != SENT) { sh_prev[par][tid] = b; nb = false; }
                }
                if (__any(na || nb)) __builtin_amdgcn_s_sleep(1);
            }
        }
        __syncthreads();   // staged row(s) visible to all waves

        float acc0 = 0.f, acc1 = 0.f;

        if (needOwn) {  // Wh[l] . h_l(t-1)
            #pragma unroll
            for (int j = 0; j < 4; ++j) {
                uint4 hv = ((const uint4*)sh_own[par])[k + 64 * j];
                acc0 = dot2(wA[4 * j + 0], hv.x, acc0);
                acc0 = dot2(wA[4 * j + 1], hv.y, acc0);
                acc0 = dot2(wA[4 * j + 2], hv.z, acc0);
                acc0 = dot2(wA[4 * j + 3], hv.w, acc0);
                acc1 = dot2(wA[16 + 4 * j + 0], hv.x, acc1);
                acc1 = dot2(wA[16 + 4 * j + 1], hv.y, acc1);
                acc1 = dot2(wA[16 + 4 * j + 2], hv.z, acc1);
                acc1 = dot2(wA[16 + 4 * j + 3], hv.w, acc1);
            }
        }
        if (needPrev) { // + Whh[l-1] . h_{l-1}(t)
            #pragma unroll
            for (int j = 0; j < 4; ++j) {
                uint4 gv = ((const uint4*)sh_prev[par])[k + 64 * j];
                acc0 = dot2(wB[4 * j + 0], gv.x, acc0);
                acc0 = dot2(wB[4 * j + 1], gv.y, acc0);
                acc0 = dot2(wB[4 * j + 2], gv.z, acc0);
                acc0 = dot2(wB[4 * j + 3], gv.w, acc0);
                acc1 = dot2(wB[16 + 4 * j + 0], gv.x, acc1);
                acc1 = dot2(wB[16 + 4 * j + 1], gv.y, acc1);
                acc1 = dot2(wB[16 + 4 * j + 2], gv.z, acc1);
                acc1 = dot2(wB[16 + 4 * j + 3], gv.w, acc1);
            }
        }

        // wave-wide butterfly reduce (both rows)
        #pragma unroll
        for (int off = 32; off > 0; off >>= 1) {
            acc0 += __shfl_xor(acc0, off, 64);
            acc1 += __shfl_xor(acc1, off, 64);
        }

        if (k == 0) {
            float a0 = acc0 + bh0, a1 = acc1 + bh1;
            if (l == 0) { a0 += xv.x; a1 += xv.y; }
            float h0 = tanhf(a0);
            float h1 = tanhf(a1);
            // the store IS the release signal (word becomes non-NaN)
            __hip_atomic_store(&histL[(size_t)t * H2 + (r0 >> 1)], packh2(h0, h1),
                               __ATOMIC_RELAXED, __HIP_MEMORY_SCOPE_AGENT);
            if (t == S_LEN - 1) {
                hfin[l * HID + r0]     = h0;
                hfin[l * HID + r0 + 1] = h1;
            }
        }
        // no trailing barrier: next iteration uses the other LDS parity
    }
}

// ---------------------------------------------------------------------------
// GEMM1: xin[t][r] = sum_k x[t][k] * Wx[r][k]   (fp32 NT-GEMM, 64x64 tile)
// ---------------------------------------------------------------------------
__global__ __launch_bounds__(256) void gemm_xin(
    const float* __restrict__ A, const float* __restrict__ B,
    float* __restrict__ C, int M, int N, int K)
{
    __shared__ float As[32][65];
    __shared__ float Bs[32][65];

    const int tid = threadIdx.x;
    const int tx = tid & 15, ty = tid >> 4;
    const int i0 = blockIdx.y * 64;
    const int j0 = blockIdx.x * 64;

    float acc[4][4] = {};

    for (int k0 = 0; k0 < K; k0 += 32) {
        #pragma unroll
        for (int ld = tid; ld < 64 * 32; ld += 256) {
            const int r = ld >> 5, kk = ld & 31;
            As[kk][r] = A[(size_t)(i0 + r) * K + k0 + kk];
            Bs[kk][r] = B[(size_t)(j0 + r) * K + k0 + kk];
        }
        __syncthreads();
        #pragma unroll
        for (int kk = 0; kk < 32; ++kk) {
            float a[4], b[4];
            #pragma unroll
            for (int u = 0; u < 4; ++u) a[u] = As[kk][ty * 4 + u];
            #pragma unroll
            for (int u = 0; u < 4; ++u) b[u] = Bs[kk][tx * 4 + u];
            #pragma unroll
            for (int u = 0; u < 4; ++u)
                #pragma unroll
                for (int q = 0; q < 4; ++q)
                    acc[u][q] += a[u] * b[q];
        }
        __syncthreads();
    }
    #pragma unroll
    for (int u = 0; u < 4; ++u)
        #pragma unroll
        for (int q = 0; q < 4; ++q)
            C[(size_t)(i0 + ty * 4 + u) * N + j0 + tx * 4 + q] = acc[u][q];
}

// ---------------------------------------------------------------------------
// Output GEMM: ys[t][j] = sum_k h3[t][k] * Wy[j][k] + By[j]
// A = hist[3] packed half2 [2048][1024u], B = Wy fp32 [1024][2048].
// ---------------------------------------------------------------------------
__global__ __launch_bounds__(256) void gemm_out(
    const uint32* __restrict__ A2, const float* __restrict__ B,
    const float* __restrict__ bias, float* __restrict__ C)
{
    __shared__ float As[32][65];
    __shared__ float Bs[32][65];

    const int tid = threadIdx.x;
    const int tx = tid & 15, ty = tid >> 4;
    const int i0 = blockIdx.y * 64;   // over M = S_LEN
    const int j0 = blockIdx.x * 64;   // over N = IN_SZ

    float acc[4][4] = {};

    for (int k0 = 0; k0 < HID; k0 += 32) {
        #pragma unroll
        for (int ld = tid; ld < 1024; ld += 256) {   // A: 64 rows x 16 uints
            const int r = ld >> 4, kk2 = ld & 15;
            half2_t h = __builtin_bit_cast(half2_t,
                A2[(size_t)(i0 + r) * H2 + (k0 >> 1) + kk2]);
            As[2 * kk2][r]     = (float)h.x;
            As[2 * kk2 + 1][r] = (float)h.y;
        }
        #pragma unroll
        for (int ld = tid; ld < 2048; ld += 256) {   // B: 64 rows x 32 k
            const int rn = ld >> 5, kk = ld & 31;
            Bs[kk][rn] = B[(size_t)(j0 + rn) * HID + k0 + kk];
        }
        __syncthreads();
        #pragma unroll
        for (int kk = 0; kk < 32; ++kk) {
            float a[4], b[4];
            #pragma unroll
            for (int u = 0; u < 4; ++u) a[u] = As[kk][ty * 4 + u];
            #pragma unroll
            for (int u = 0; u < 4; ++u) b[u] = Bs[kk][tx * 4 + u];
            #pragma unroll
            for (int u = 0; u < 4; ++u)
                #pragma unroll
                for (int q = 0; q < 4; ++q)
                    acc[u][q] += a[u] * b[q];
        }
        __syncthreads();
    }
    #pragma unroll
    for (int u = 0; u < 4; ++u)
        #pragma unroll
        for (int q = 0; q < 4; ++q) {
            const int i = i0 + ty * 4 + u;
            const int j = j0 + tx * 4 + q;
            C[(size_t)i * IN_SZ + j] = acc[u][q] + bias[j];
        }
}

// ---------------------------------------------------------------------------
extern "C" void kernel_launch(void* const* d_in, const int* in_sizes, int n_in,
                              void* d_out, int out_size, void* d_ws, size_t ws_size,
                              hipStream_t stream) {
    const float* x   = (const float*)d_in[0];
    const float* Wh  = (const float*)d_in[1];
    const float* Whh = (const float*)d_in[2];
    const float* Wx  = (const float*)d_in[3];
    const float* Wy  = (const float*)d_in[4];
    const float* Bh  = (const float*)d_in[5];
    const float* By  = (const float*)d_in[6];

    float* out  = (float*)d_out;
    float* hfin = out + (size_t)S_LEN * IN_SZ;

    // ws layout: [xin S*H fp32 = 16 MB][hist 4*S*H2 u32 = 32 MB]
    float*  xin  = (float*)d_ws;
    uint32* hist = (uint32*)d_ws + (size_t)S_LEN * HID;

    // sentinel-fill hist: 0x7F byte -> each fp16 half = NaN (never produced)
    hipMemsetAsync(hist, 0x7F, (size_t)NLAY * S_LEN * H2 * sizeof(uint32), stream);

    // xin = x @ Wx^T  (M=S, N=H, K=IN)
    gemm_xin<<<dim3(HID / 64, S_LEN / 64), 256, 0, stream>>>(
        x, Wx, xin, S_LEN, HID, IN_SZ);

    // the sequential scan (persistent, 1 WG per CU)
    rnn_scan<<<NWG, BLK, 0, stream>>>(Wh, Whh, xin, Bh, hfin, hist);

    // ys = H3 @ Wy^T + By  -> d_out
    gemm_out<<<dim3(IN_SZ / 64, S_LEN / 64), 256, 0, stream>>>(
        hist + (size_t)3 * S_LEN * H2, Wy, By, out);
}

// Round 6
// 7305.592 us; speedup vs baseline: 14.0986x; 1.2317x over previous
//
#include <hip/hip_runtime.h>
#include <math.h>

// ---------------------------------------------------------------------------
// RNNv2 round 6: data-as-signal + barrier-free async chunk pipeline in-WG.
//   - 256 WGs x 1024 thr; WG g -> layer l=g>>6, wg-in-layer w=g&63.
//   - Weights persist in packed-half2 VGPRs (wA=Wh rows, wB=Whh rows).
//   - hist[l][t][H2] packed half2, sentinel 0x7F7F7F7F (fp16 NaN) = not ready.
//   - Per step: each wave spin-loads its 64 own + 64 prev words from L3,
//     stages to LDS, bumps LDS chunk flags (monotonic counters, parity-gated
//     by a done counter). Waves consume chunks as they become ready:
//     prev first (off critical path), then own chunks 0..3. No __syncthreads
//     in the loop; the last-arriving chunk's tail is ~8 dot2 + reduce.
// d_out = [ys (S*IN) | h_final (L*H)]
// ---------------------------------------------------------------------------

typedef unsigned int uint32;
typedef unsigned long long uint64;
typedef _Float16 half2_t __attribute__((ext_vector_type(2)));

#define S_LEN 2048
#define IN_SZ 1024
#define HID   2048
#define NLAY  4
#define NWG   256
#define BLK   1024
#define H2    1024   // uints per packed h vector (HID/2)
#define SENT  0x7F7F7F7Fu

#define LD_AGENT(p)  __hip_atomic_load((p), __ATOMIC_RELAXED, __HIP_MEMORY_SCOPE_AGENT)
#define ST_AGENT(p,v) __hip_atomic_store((p), (v), __ATOMIC_RELAXED, __HIP_MEMORY_SCOPE_AGENT)
#define LDS_ACQ(p)   __hip_atomic_load((p), __ATOMIC_ACQUIRE, __HIP_MEMORY_SCOPE_WORKGROUP)
#define LDS_RELADD(p) __hip_atomic_fetch_add((p), 1u, __ATOMIC_RELEASE, __HIP_MEMORY_SCOPE_WORKGROUP)

__device__ __forceinline__ float dot2(uint32 a, uint32 b, float c) {
    return __builtin_amdgcn_fdot2(__builtin_bit_cast(half2_t, a),
                                  __builtin_bit_cast(half2_t, b), c, false);
}
__device__ __forceinline__ uint32 packh2(float x, float y) {
    half2_t h; h.x = (_Float16)x; h.y = (_Float16)y;   // RNE converts
    return __builtin_bit_cast(uint32, h);
}

__global__ __launch_bounds__(BLK, 4) void rnn_scan(
    const float* __restrict__ Wh,   // [4][H][H]
    const float* __restrict__ Whh,  // [3][H][H]
    const float* __restrict__ xin,  // [S][H]  (x @ Wx^T, fp32)
    const float* __restrict__ Bh,   // [4][H]
    float* __restrict__ hfin,       // [4][H] (tail of d_out)
    uint32* hist)                   // [4][S][H2] packed half2, sentinel-filled
{
    __shared__ __align__(16) uint32 sh_own[2][H2];
    __shared__ __align__(16) uint32 sh_prev[2][H2];
    __shared__ uint32 ownFlag[2][4];   // +4 per use (16 waves / 4 chunks)
    __shared__ uint32 prevFlag[2];     // +16 per use
    __shared__ uint32 doneCnt[2];      // +16 per use (1 per wave)

    const int g   = blockIdx.x;
    const int l   = g >> 6;          // layer 0..3 (wave-uniform)
    const int w   = g & 63;          // wg within layer
    const int tid = threadIdx.x;
    const int v   = tid >> 6;        // wave 0..15
    const int k   = tid & 63;        // lane
    const int r0  = w * 32 + v * 2;  // first of this wave's 2 rows

    if (tid < 8) ((uint32*)ownFlag)[tid] = 0;
    if (tid < 2) { prevFlag[tid] = 0; doneCnt[tid] = 0; }

    // ---- one-time: load + pack weights into registers --------------------
    // Chunk c (0..3): lane k covers cols 8k+512c..+7 = uint4 index k+64c.
    uint32 wA[32], wB[32];
    const float bh0 = Bh[l * HID + r0];
    const float bh1 = Bh[l * HID + r0 + 1];

    #pragma unroll
    for (int rr = 0; rr < 2; ++rr) {
        const float* wr = Wh + ((size_t)l * HID + r0 + rr) * HID;
        #pragma unroll
        for (int j = 0; j < 4; ++j) {
            const float* p = wr + 8 * k + 512 * j;
            float4 f0 = *(const float4*)p;
            float4 f1 = *(const float4*)(p + 4);
            wA[16 * rr + 4 * j + 0] = packh2(f0.x, f0.y);
            wA[16 * rr + 4 * j + 1] = packh2(f0.z, f0.w);
            wA[16 * rr + 4 * j + 2] = packh2(f1.x, f1.y);
            wA[16 * rr + 4 * j + 3] = packh2(f1.z, f1.w);
        }
    }
    if (l > 0) {
        #pragma unroll
        for (int rr = 0; rr < 2; ++rr) {
            const float* wr2 = Whh + ((size_t)(l - 1) * HID + r0 + rr) * HID;
            #pragma unroll
            for (int j = 0; j < 4; ++j) {
                const float* p = wr2 + 8 * k + 512 * j;
                float4 f0 = *(const float4*)p;
                float4 f1 = *(const float4*)(p + 4);
                wB[16 * rr + 4 * j + 0] = packh2(f0.x, f0.y);
                wB[16 * rr + 4 * j + 1] = packh2(f0.z, f0.w);
                wB[16 * rr + 4 * j + 2] = packh2(f1.x, f1.y);
                wB[16 * rr + 4 * j + 3] = packh2(f1.z, f1.w);
            }
        }
    }

    uint32* histL = hist + (size_t)l * S_LEN * H2;
    uint32* histP = hist + (size_t)(l - 1) * S_LEN * H2;  // only if l>0

    __syncthreads();   // counters initialized (only barrier in the kernel)

    // ---- timestep loop ----------------------------------------------------
    for (int t = 0; t < S_LEN; ++t) {
        const int    p = t & 1;
        const uint32 n = (uint32)(t >> 1);
        const bool needOwn  = (t > 0);
        const bool needPrev = (l > 0);

        // layer 0: prefetch xin pair early (static data)
        float2 xv = make_float2(0.f, 0.f);
        if (l == 0) xv = *(const float2*)(xin + (size_t)t * HID + r0);

        // parity-buffer reuse gate: all 16 waves done with step t-2
        if (t >= 2) {
            while (LDS_ACQ(&doneCnt[p]) < 16u * n)
                __builtin_amdgcn_s_sleep(1);
        }

        // ---- stage: spin-load own+prev words, LDS + chunk flags ----------
        {
            uint32 aOwn = 0, aPrev = 0;
            bool gotO = !needOwn, gotP = !needPrev;
            bool flgO = false, flgP = (l == 0);
            const uint32* pOwn  = histL + (size_t)(needOwn ? t - 1 : 0) * H2 + tid;
            const uint32* pPrev = histP + (size_t)t * H2 + tid;
            for (;;) {
                if (!flgP) {
                    if (!gotP) {
                        uint32 b = LD_AGENT(pPrev);
                        if (b != SENT) { aPrev = b; gotP = true; }
                    }
                    if (__all(gotP)) {
                        sh_prev[p][tid] = aPrev;
                        if (k == 0) LDS_RELADD(&prevFlag[p]);
                        flgP = true;
                    }
                }
                if (!flgO) {
                    if (!gotO) {
                        uint32 a = LD_AGENT(pOwn);
                        if (a != SENT) { aOwn = a; gotO = true; }
                    }
                    if (__all(gotO)) {
                        if (needOwn) sh_own[p][tid] = aOwn;
                        if (k == 0) LDS_RELADD(&ownFlag[p][v >> 2]);
                        flgO = true;
                    }
                }
                if (flgO && flgP) break;
                __builtin_amdgcn_s_sleep(2);
            }
        }

        // ---- compute: prev first (off critical path), then own chunks ----
        float acc0 = 0.f, acc1 = 0.f;

        if (needPrev) {
            while (LDS_ACQ(&prevFlag[p]) < 16u * (n + 1))
                __builtin_amdgcn_s_sleep(1);
            #pragma unroll
            for (int j = 0; j < 4; ++j) {
                uint4 gv = ((const uint4*)sh_prev[p])[k + 64 * j];
                acc0 = dot2(wB[4 * j + 0], gv.x, acc0);
                acc0 = dot2(wB[4 * j + 1], gv.y, acc0);
                acc0 = dot2(wB[4 * j + 2], gv.z, acc0);
                acc0 = dot2(wB[4 * j + 3], gv.w, acc0);
                acc1 = dot2(wB[16 + 4 * j + 0], gv.x, acc1);
                acc1 = dot2(wB[16 + 4 * j + 1], gv.y, acc1);
                acc1 = dot2(wB[16 + 4 * j + 2], gv.z, acc1);
                acc1 = dot2(wB[16 + 4 * j + 3], gv.w, acc1);
            }
        }

        if (needOwn) {
            #pragma unroll
            for (int c = 0; c < 4; ++c) {
                while (LDS_ACQ(&ownFlag[p][c]) < 4u * (n + 1))
                    __builtin_amdgcn_s_sleep(1);
                uint4 hv = ((const uint4*)sh_own[p])[k + 64 * c];
                acc0 = dot2(wA[4 * c + 0], hv.x, acc0);
                acc0 = dot2(wA[4 * c + 1], hv.y, acc0);
                acc0 = dot2(wA[4 * c + 2], hv.z, acc0);
                acc0 = dot2(wA[4 * c + 3], hv.w, acc0);
                acc1 = dot2(wA[16 + 4 * c + 0], hv.x, acc1);
                acc1 = dot2(wA[16 + 4 * c + 1], hv.y, acc1);
                acc1 = dot2(wA[16 + 4 * c + 2], hv.z, acc1);
                acc1 = dot2(wA[16 + 4 * c + 3], hv.w, acc1);
            }
        }

        // wave-wide butterfly reduce (both rows)
        #pragma unroll
        for (int off = 32; off > 0; off >>= 1) {
            acc0 += __shfl_xor(acc0, off, 64);
            acc1 += __shfl_xor(acc1, off, 64);
        }

        if (k == 0) {
            float a0 = acc0 + bh0, a1 = acc1 + bh1;
            if (l == 0) { a0 += xv.x; a1 += xv.y; }
            float h0 = tanhf(a0);
            float h1 = tanhf(a1);
            // the store IS the release signal (word becomes non-NaN)
            ST_AGENT(&histL[(size_t)t * H2 + (r0 >> 1)], packh2(h0, h1));
            if (t == S_LEN - 1) {
                hfin[l * HID + r0]     = h0;
                hfin[l * HID + r0 + 1] = h1;
            }
            LDS_RELADD(&doneCnt[p]);   // wave finished consuming parity p
        }
    }
}

// ---------------------------------------------------------------------------
// GEMM1: xin[t][r] = sum_k x[t][k] * Wx[r][k]   (fp32 NT-GEMM, 64x64 tile)
// ---------------------------------------------------------------------------
__global__ __launch_bounds__(256) void gemm_xin(
    const float* __restrict__ A, const float* __restrict__ B,
    float* __restrict__ C, int M, int N, int K)
{
    __shared__ float As[32][65];
    __shared__ float Bs[32][65];

    const int tid = threadIdx.x;
    const int tx = tid & 15, ty = tid >> 4;
    const int i0 = blockIdx.y * 64;
    const int j0 = blockIdx.x * 64;

    float acc[4][4] = {};

    for (int k0 = 0; k0 < K; k0 += 32) {
        #pragma unroll
        for (int ld = tid; ld < 64 * 32; ld += 256) {
            const int r = ld >> 5, kk = ld & 31;
            As[kk][r] = A[(size_t)(i0 + r) * K + k0 + kk];
            Bs[kk][r] = B[(size_t)(j0 + r) * K + k0 + kk];
        }
        __syncthreads();
        #pragma unroll
        for (int kk = 0; kk < 32; ++kk) {
            float a[4], b[4];
            #pragma unroll
            for (int u = 0; u < 4; ++u) a[u] = As[kk][ty * 4 + u];
            #pragma unroll
            for (int u = 0; u < 4; ++u) b[u] = Bs[kk][tx * 4 + u];
            #pragma unroll
            for (int u = 0; u < 4; ++u)
                #pragma unroll
                for (int q = 0; q < 4; ++q)
                    acc[u][q] += a[u] * b[q];
        }
        __syncthreads();
    }
    #pragma unroll
    for (int u = 0; u < 4; ++u)
        #pragma unroll
        for (int q = 0; q < 4; ++q)
            C[(size_t)(i0 + ty * 4 + u) * N + j0 + tx * 4 + q] = acc[u][q];
}

// ---------------------------------------------------------------------------
// Output GEMM: ys[t][j] = sum_k h3[t][k] * Wy[j][k] + By[j]
// A = hist[3] packed half2 [2048][1024u], B = Wy fp32 [1024][2048].
// ---------------------------------------------------------------------------
__global__ __launch_bounds__(256) void gemm_out(
    const uint32* __restrict__ A2, const float* __restrict__ B,
    const float* __restrict__ bias, float* __restrict__ C)
{
    __shared__ float As[32][65];
    __shared__ float Bs[32][65];

    const int tid = threadIdx.x;
    const int tx = tid & 15, ty = tid >> 4;
    const int i0 = blockIdx.y * 64;   // over M = S_LEN
    const int j0 = blockIdx.x * 64;   // over N = IN_SZ

    float acc[4][4] = {};

    for (int k0 = 0; k0 < HID; k0 += 32) {
        #pragma unroll
        for (int ld = tid; ld < 1024; ld += 256) {   // A: 64 rows x 16 uints
            const int r = ld >> 4, kk2 = ld & 15;
            half2_t h = __builtin_bit_cast(half2_t,
                A2[(size_t)(i0 + r) * H2 + (k0 >> 1) + kk2]);
            As[2 * kk2][r]     = (float)h.x;
            As[2 * kk2 + 1][r] = (float)h.y;
        }
        #pragma unroll
        for (int ld = tid; ld < 2048; ld += 256) {   // B: 64 rows x 32 k
            const int rn = ld >> 5, kk = ld & 31;
            Bs[kk][rn] = B[(size_t)(j0 + rn) * HID + k0 + kk];
        }
        __syncthreads();
        #pragma unroll
        for (int kk = 0; kk < 32; ++kk) {
            float a[4], b[4];
            #pragma unroll
            for (int u = 0; u < 4; ++u) a[u] = As[kk][ty * 4 + u];
            #pragma unroll
            for (int u = 0; u < 4; ++u) b[u] = Bs[kk][tx * 4 + u];
            #pragma unroll
            for (int u = 0; u < 4; ++u)
                #pragma unroll
                for (int q = 0; q < 4; ++q)
                    acc[u][q] += a[u] * b[q];
        }
        __syncthreads();
    }
    #pragma unroll
    for (int u = 0; u < 4; ++u)
        #pragma unroll
        for (int q = 0; q < 4; ++q) {
            const int i = i0 + ty * 4 + u;
            const int j = j0 + tx * 4 + q;
            C[(size_t)i * IN_SZ + j] = acc[u][q] + bias[j];
        }
}

// ---------------------------------------------------------------------------
extern "C" void kernel_launch(void* const* d_in, const int* in_sizes, int n_in,
                              void* d_out, int out_size, void* d_ws, size_t ws_size,
                              hipStream_t stream) {
    const float* x   = (const float*)d_in[0];
    const float* Wh  = (const float*)d_in[1];
    const float* Whh = (const float*)d_in[2];
    const float* Wx  = (const float*)d_in[3];
    const float* Wy  = (const float*)d_in[4];
    const float* Bh  = (const float*)d_in[5];
    const float* By  = (const float*)d_in[6];

    float* out  = (float*)d_out;
    float* hfin = out + (size_t)S_LEN * IN_SZ;

    // ws layout: [xin S*H fp32 = 16 MB][hist 4*S*H2 u32 = 32 MB]
    float*  xin  = (float*)d_ws;
    uint32* hist = (uint32*)d_ws + (size_t)S_LEN * HID;

    // sentinel-fill hist: 0x7F byte -> each fp16 half = NaN (never produced)
    hipMemsetAsync(hist, 0x7F, (size_t)NLAY * S_LEN * H2 * sizeof(uint32), stream);

    // xin = x @ Wx^T  (M=S, N=H, K=IN)
    gemm_xin<<<dim3(HID / 64, S_LEN / 64), 256, 0, stream>>>(
        x, Wx, xin, S_LEN, HID, IN_SZ);

    // the sequential scan (persistent, 1 WG per CU)
    rnn_scan<<<NWG, BLK, 0, stream>>>(Wh, Whh, xin, Bh, hfin, hist);

    // ys = H3 @ Wy^T + By  -> d_out
    gemm_out<<<dim3(IN_SZ / 64, S_LEN / 64), 256, 0, stream>>>(
        hist + (size_t)3 * S_LEN * H2, Wy, By, out);
}

// Round 7
// 7240.307 us; speedup vs baseline: 14.2257x; 1.0090x over previous
//
#include <hip/hip_runtime.h>
#include <math.h>

// ---------------------------------------------------------------------------
// RNNv2 round 7: same data-as-signal async-chunk dataflow as round 6, but
//   - BLK=512 (8 waves/WG, 4 rows/wave), __launch_bounds__(512,2):
//     256-VGPR budget -> 128 weight words/lane live in TRUE VGPRs
//     (round 6's 1024x4 shape forced them into AGPRs -> v_accvgpr_read
//     on every dot2 operand, ~2x VALU on the critical tail).
//   - 2 waves/SIMD: spin waves no longer crowd the critical wave's issue.
//   - s_setprio(1) in compute, s_setprio(0) while spinning.
//   - one uint64 h-store per wave (4 rows).
// d_out = [ys (S*IN) | h_final (L*H)]
// ---------------------------------------------------------------------------

typedef unsigned int uint32;
typedef unsigned long long uint64;
typedef _Float16 half2_t __attribute__((ext_vector_type(2)));

#define S_LEN 2048
#define IN_SZ 1024
#define HID   2048
#define NLAY  4
#define NWG   256
#define BLK   512
#define H2    1024   // uints per packed h vector (HID/2)
#define SENT  0x7F7F7F7Fu

#define LD_AGENT(p)   __hip_atomic_load((p), __ATOMIC_RELAXED, __HIP_MEMORY_SCOPE_AGENT)
#define ST_AGENT(p,v) __hip_atomic_store((p), (v), __ATOMIC_RELAXED, __HIP_MEMORY_SCOPE_AGENT)
#define LDS_ACQ(p)    __hip_atomic_load((p), __ATOMIC_ACQUIRE, __HIP_MEMORY_SCOPE_WORKGROUP)
#define LDS_RELADD(p) __hip_atomic_fetch_add((p), 1u, __ATOMIC_RELEASE, __HIP_MEMORY_SCOPE_WORKGROUP)

__device__ __forceinline__ float dot2(uint32 a, uint32 b, float c) {
    return __builtin_amdgcn_fdot2(__builtin_bit_cast(half2_t, a),
                                  __builtin_bit_cast(half2_t, b), c, false);
}
__device__ __forceinline__ uint32 packh2(float x, float y) {
    half2_t h; h.x = (_Float16)x; h.y = (_Float16)y;   // RNE converts
    return __builtin_bit_cast(uint32, h);
}

__global__ __launch_bounds__(BLK, 2) void rnn_scan(
    const float* __restrict__ Wh,   // [4][H][H]
    const float* __restrict__ Whh,  // [3][H][H]
    const float* __restrict__ xin,  // [S][H]  (x @ Wx^T, fp32)
    const float* __restrict__ Bh,   // [4][H]
    float* __restrict__ hfin,       // [4][H] (tail of d_out)
    uint32* hist)                   // [4][S][H2] packed half2, sentinel-filled
{
    __shared__ __align__(16) uint32 sh_own[2][H2];
    __shared__ __align__(16) uint32 sh_prev[2][H2];
    __shared__ uint32 ownFlag[2][4];   // +4 per step (8 waves x 2 sub-slices / 4 chunks)
    __shared__ uint32 prevFlag[2][4];  // +4 per step (l>0 only)
    __shared__ uint32 doneCnt[2];      // +8 per step (1 per wave)

    const int g   = blockIdx.x;
    const int l   = g >> 6;          // layer 0..3 (wave-uniform)
    const int w   = g & 63;          // wg within layer
    const int tid = threadIdx.x;
    const int v   = tid >> 6;        // wave 0..7
    const int k   = tid & 63;        // lane
    const int r0  = w * 32 + v * 4;  // first of this wave's 4 rows

    if (tid < 8)  ((uint32*)ownFlag)[tid]  = 0;
    if (tid < 8)  ((uint32*)prevFlag)[tid] = 0;
    if (tid < 2)  doneCnt[tid] = 0;

    // ---- one-time: load + pack weights into TRUE VGPRs -------------------
    // Chunk c (0..3): lane k covers cols 8k+512c..+7 = uint4 index k+64c of
    // the packed h row. wA[16*rr + 4c + q] = Wh row rr; wB likewise for Whh.
    uint32 wA[64], wB[64];
    const float4 bh4 = *(const float4*)(Bh + l * HID + r0);

    #pragma unroll
    for (int rr = 0; rr < 4; ++rr) {
        const float* wr = Wh + ((size_t)l * HID + r0 + rr) * HID;
        #pragma unroll
        for (int j = 0; j < 4; ++j) {
            const float* p = wr + 8 * k + 512 * j;
            float4 f0 = *(const float4*)p;
            float4 f1 = *(const float4*)(p + 4);
            wA[16 * rr + 4 * j + 0] = packh2(f0.x, f0.y);
            wA[16 * rr + 4 * j + 1] = packh2(f0.z, f0.w);
            wA[16 * rr + 4 * j + 2] = packh2(f1.x, f1.y);
            wA[16 * rr + 4 * j + 3] = packh2(f1.z, f1.w);
        }
    }
    if (l > 0) {
        #pragma unroll
        for (int rr = 0; rr < 4; ++rr) {
            const float* wr2 = Whh + ((size_t)(l - 1) * HID + r0 + rr) * HID;
            #pragma unroll
            for (int j = 0; j < 4; ++j) {
                const float* p = wr2 + 8 * k + 512 * j;
                float4 f0 = *(const float4*)p;
                float4 f1 = *(const float4*)(p + 4);
                wB[16 * rr + 4 * j + 0] = packh2(f0.x, f0.y);
                wB[16 * rr + 4 * j + 1] = packh2(f0.z, f0.w);
                wB[16 * rr + 4 * j + 2] = packh2(f1.x, f1.y);
                wB[16 * rr + 4 * j + 3] = packh2(f1.z, f1.w);
            }
        }
    }

    uint32* histL = hist + (size_t)l * S_LEN * H2;
    uint32* histP = hist + (size_t)(l - 1) * S_LEN * H2;  // only if l>0

    __syncthreads();   // counters initialized (only barrier in the kernel)

    // ---- timestep loop ----------------------------------------------------
    // Thread stages own/prev words {tid, tid+512}. Word m belongs to chunk
    // m>>8: first-half word tid -> chunk v>>2 (0..1); second-half -> 2+(v>>2).
    const int c0 = v >> 2;       // chunk of first-half slice
    const int c1 = 2 + (v >> 2); // chunk of second-half slice

    for (int t = 0; t < S_LEN; ++t) {
        const int    p = t & 1;
        const uint32 n = (uint32)(t >> 1);
        const bool needOwn  = (t > 0);
        const bool needPrev = (l > 0);

        // layer 0: prefetch xin quad early (static data)
        float4 xv = make_float4(0.f, 0.f, 0.f, 0.f);
        if (l == 0 && k == 0) xv = *(const float4*)(xin + (size_t)t * HID + r0);

        // parity-buffer reuse gate: all 8 waves done with step t-2
        if (t >= 2) {
            while (LDS_ACQ(&doneCnt[p]) < 8u * n) {
                __builtin_amdgcn_s_setprio(0);
                __builtin_amdgcn_s_sleep(1);
            }
        }
        __builtin_amdgcn_s_setprio(1);

        // ---- stage: spin-load own+prev word pairs, LDS + chunk flags -----
        {
            uint32 a0 = 0, a1 = 0, b0 = 0, b1 = 0;
            bool gO0 = !needOwn, gO1 = !needOwn;
            bool gP0 = !needPrev, gP1 = !needPrev;
            bool fO0 = false, fO1 = false;
            bool fP0 = !needPrev, fP1 = !needPrev;  // l==0: never bump prev
            const size_t tOwn = (size_t)(needOwn ? t - 1 : 0) * H2;
            const uint32* pO0 = histL + tOwn + tid;
            const uint32* pO1 = histL + tOwn + tid + 512;
            const uint32* pP0 = histP + (size_t)t * H2 + tid;
            const uint32* pP1 = histP + (size_t)t * H2 + tid + 512;
            for (;;) {
                if (!fP0) {
                    if (!gP0) { uint32 b = LD_AGENT(pP0);
                        if (b != SENT) { sh_prev[p][tid] = b; gP0 = true; } }
                    if (__all(gP0)) { if (k == 0) LDS_RELADD(&prevFlag[p][c0]); fP0 = true; }
                }
                if (!fP1) {
                    if (!gP1) { uint32 b = LD_AGENT(pP1);
                        if (b != SENT) { sh_prev[p][tid + 512] = b; gP1 = true; } }
                    if (__all(gP1)) { if (k == 0) LDS_RELADD(&prevFlag[p][c1]); fP1 = true; }
                }
                if (!fO0) {
                    if (!gO0) { uint32 a = LD_AGENT(pO0);
                        if (a != SENT) { sh_own[p][tid] = a; gO0 = true; } }
                    if (__all(gO0)) { if (k == 0) LDS_RELADD(&ownFlag[p][c0]); fO0 = true; }
                }
                if (!fO1) {
                    if (!gO1) { uint32 a = LD_AGENT(pO1);
                        if (a != SENT) { sh_own[p][tid + 512] = a; gO1 = true; } }
                    if (__all(gO1)) { if (k == 0) LDS_RELADD(&ownFlag[p][c1]); fO1 = true; }
                }
                if (fO0 && fO1 && fP0 && fP1) break;
                __builtin_amdgcn_s_setprio(0);
                __builtin_amdgcn_s_sleep(2);
            }
        }
        __builtin_amdgcn_s_setprio(1);

        // ---- compute: prev chunks first (early data), then own chunks ----
        float acc0 = 0.f, acc1 = 0.f, acc2 = 0.f, acc3 = 0.f;

        if (needPrev) {
            #pragma unroll
            for (int c = 0; c < 4; ++c) {
                while (LDS_ACQ(&prevFlag[p][c]) < 4u * (n + 1)) {
                    __builtin_amdgcn_s_setprio(0);
                    __builtin_amdgcn_s_sleep(1);
                }
                __builtin_amdgcn_s_setprio(1);
                uint4 gv = ((const uint4*)sh_prev[p])[k + 64 * c];
                acc0 = dot2(wB[4 * c + 0], gv.x, acc0);
                acc0 = dot2(wB[4 * c + 1], gv.y, acc0);
                acc0 = dot2(wB[4 * c + 2], gv.z, acc0);
                acc0 = dot2(wB[4 * c + 3], gv.w, acc0);
                acc1 = dot2(wB[16 + 4 * c + 0], gv.x, acc1);
                acc1 = dot2(wB[16 + 4 * c + 1], gv.y, acc1);
                acc1 = dot2(wB[16 + 4 * c + 2], gv.z, acc1);
                acc1 = dot2(wB[16 + 4 * c + 3], gv.w, acc1);
                acc2 = dot2(wB[32 + 4 * c + 0], gv.x, acc2);
                acc2 = dot2(wB[32 + 4 * c + 1], gv.y, acc2);
                acc2 = dot2(wB[32 + 4 * c + 2], gv.z, acc2);
                acc2 = dot2(wB[32 + 4 * c + 3], gv.w, acc2);
                acc3 = dot2(wB[48 + 4 * c + 0], gv.x, acc3);
                acc3 = dot2(wB[48 + 4 * c + 1], gv.y, acc3);
                acc3 = dot2(wB[48 + 4 * c + 2], gv.z, acc3);
                acc3 = dot2(wB[48 + 4 * c + 3], gv.w, acc3);
            }
        }

        if (needOwn) {
            #pragma unroll
            for (int c = 0; c < 4; ++c) {
                while (LDS_ACQ(&ownFlag[p][c]) < 4u * (n + 1)) {
                    __builtin_amdgcn_s_setprio(0);
                    __builtin_amdgcn_s_sleep(1);
                }
                __builtin_amdgcn_s_setprio(1);
                uint4 hv = ((const uint4*)sh_own[p])[k + 64 * c];
                acc0 = dot2(wA[4 * c + 0], hv.x, acc0);
                acc0 = dot2(wA[4 * c + 1], hv.y, acc0);
                acc0 = dot2(wA[4 * c + 2], hv.z, acc0);
                acc0 = dot2(wA[4 * c + 3], hv.w, acc0);
                acc1 = dot2(wA[16 + 4 * c + 0], hv.x, acc1);
                acc1 = dot2(wA[16 + 4 * c + 1], hv.y, acc1);
                acc1 = dot2(wA[16 + 4 * c + 2], hv.z, acc1);
                acc1 = dot2(wA[16 + 4 * c + 3], hv.w, acc1);
                acc2 = dot2(wA[32 + 4 * c + 0], hv.x, acc2);
                acc2 = dot2(wA[32 + 4 * c + 1], hv.y, acc2);
                acc2 = dot2(wA[32 + 4 * c + 2], hv.z, acc2);
                acc2 = dot2(wA[32 + 4 * c + 3], hv.w, acc2);
                acc3 = dot2(wA[48 + 4 * c + 0], hv.x, acc3);
                acc3 = dot2(wA[48 + 4 * c + 1], hv.y, acc3);
                acc3 = dot2(wA[48 + 4 * c + 2], hv.z, acc3);
                acc3 = dot2(wA[48 + 4 * c + 3], hv.w, acc3);
            }
        }

        // wave-wide butterfly reduce (4 rows)
        #pragma unroll
        for (int off = 32; off > 0; off >>= 1) {
            acc0 += __shfl_xor(acc0, off, 64);
            acc1 += __shfl_xor(acc1, off, 64);
            acc2 += __shfl_xor(acc2, off, 64);
            acc3 += __shfl_xor(acc3, off, 64);
        }

        if (k == 0) {
            float h0 = tanhf(acc0 + bh4.x + (l == 0 ? xv.x : 0.f));
            float h1 = tanhf(acc1 + bh4.y + (l == 0 ? xv.y : 0.f));
            float h2 = tanhf(acc2 + bh4.z + (l == 0 ? xv.z : 0.f));
            float h3 = tanhf(acc3 + bh4.w + (l == 0 ? xv.w : 0.f));
            // single 8B store IS the release signal (words become non-NaN)
            uint64 hw = (uint64)packh2(h0, h1) | ((uint64)packh2(h2, h3) << 32);
            ST_AGENT((uint64*)&histL[(size_t)t * H2 + (r0 >> 1)], hw);
            if (t == S_LEN - 1) {
                hfin[l * HID + r0]     = h0;
                hfin[l * HID + r0 + 1] = h1;
                hfin[l * HID + r0 + 2] = h2;
                hfin[l * HID + r0 + 3] = h3;
            }
            LDS_RELADD(&doneCnt[p]);   // wave finished consuming parity p
        }
    }
}

// ---------------------------------------------------------------------------
// GEMM1: xin[t][r] = sum_k x[t][k] * Wx[r][k]   (fp32 NT-GEMM, 64x64 tile)
// ---------------------------------------------------------------------------
__global__ __launch_bounds__(256) void gemm_xin(
    const float* __restrict__ A, const float* __restrict__ B,
    float* __restrict__ C, int M, int N, int K)
{
    __shared__ float As[32][65];
    __shared__ float Bs[32][65];

    const int tid = threadIdx.x;
    const int tx = tid & 15, ty = tid >> 4;
    const int i0 = blockIdx.y * 64;
    const int j0 = blockIdx.x * 64;

    float acc[4][4] = {};

    for (int k0 = 0; k0 < K; k0 += 32) {
        #pragma unroll
        for (int ld = tid; ld < 64 * 32; ld += 256) {
            const int r = ld >> 5, kk = ld & 31;
            As[kk][r] = A[(size_t)(i0 + r) * K + k0 + kk];
            Bs[kk][r] = B[(size_t)(j0 + r) * K + k0 + kk];
        }
        __syncthreads();
        #pragma unroll
        for (int kk = 0; kk < 32; ++kk) {
            float a[4], b[4];
            #pragma unroll
            for (int u = 0; u < 4; ++u) a[u] = As[kk][ty * 4 + u];
            #pragma unroll
            for (int u = 0; u < 4; ++u) b[u] = Bs[kk][tx * 4 + u];
            #pragma unroll
            for (int u = 0; u < 4; ++u)
                #pragma unroll
                for (int q = 0; q < 4; ++q)
                    acc[u][q] += a[u] * b[q];
        }
        __syncthreads();
    }
    #pragma unroll
    for (int u = 0; u < 4; ++u)
        #pragma unroll
        for (int q = 0; q < 4; ++q)
            C[(size_t)(i0 + ty * 4 + u) * N + j0 + tx * 4 + q] = acc[u][q];
}

// ---------------------------------------------------------------------------
// Output GEMM: ys[t][j] = sum_k h3[t][k] * Wy[j][k] + By[j]
// A = hist[3] packed half2 [2048][1024u], B = Wy fp32 [1024][2048].
// ---------------------------------------------------------------------------
__global__ __launch_bounds__(256) void gemm_out(
    const uint32* __restrict__ A2, const float* __restrict__ B,
    const float* __restrict__ bias, float* __restrict__ C)
{
    __shared__ float As[32][65];
    __shared__ float Bs[32][65];

    const int tid = threadIdx.x;
    const int tx = tid & 15, ty = tid >> 4;
    const int i0 = blockIdx.y * 64;   // over M = S_LEN
    const int j0 = blockIdx.x * 64;   // over N = IN_SZ

    float acc[4][4] = {};

    for (int k0 = 0; k0 < HID; k0 += 32) {
        #pragma unroll
        for (int ld = tid; ld < 1024; ld += 256) {   // A: 64 rows x 16 uints
            const int r = ld >> 4, kk2 = ld & 15;
            half2_t h = __builtin_bit_cast(half2_t,
                A2[(size_t)(i0 + r) * H2 + (k0 >> 1) + kk2]);
            As[2 * kk2][r]     = (float)h.x;
            As[2 * kk2 + 1][r] = (float)h.y;
        }
        #pragma unroll
        for (int ld = tid; ld < 2048; ld += 256) {   // B: 64 rows x 32 k
            const int rn = ld >> 5, kk = ld & 31;
            Bs[kk][rn] = B[(size_t)(j0 + rn) * HID + k0 + kk];
        }
        __syncthreads();
        #pragma unroll
        for (int kk = 0; kk < 32; ++kk) {
            float a[4], b[4];
            #pragma unroll
            for (int u = 0; u < 4; ++u) a[u] = As[kk][ty * 4 + u];
            #pragma unroll
            for (int u = 0; u < 4; ++u) b[u] = Bs[kk][tx * 4 + u];
            #pragma unroll
            for (int u = 0; u < 4; ++u)
                #pragma unroll
                for (int q = 0; q < 4; ++q)
                    acc[u][q] += a[u] * b[q];
        }
        __syncthreads();
    }
    #pragma unroll
    for (int u = 0; u < 4; ++u)
        #pragma unroll
        for (int q = 0; q < 4; ++q) {
            const int i = i0 + ty * 4 + u;
            const int j = j0 + tx * 4 + q;
            C[(size_t)i * IN_SZ + j] = acc[u][q] + bias[j];
        }
}

// ---------------------------------------------------------------------------
extern "C" void kernel_launch(void* const* d_in, const int* in_sizes, int n_in,
                              void* d_out, int out_size, void* d_ws, size_t ws_size,
                              hipStream_t stream) {
    const float* x   = (const float*)d_in[0];
    const float* Wh  = (const float*)d_in[1];
    const float* Whh = (const float*)d_in[2];
    const float* Wx  = (const float*)d_in[3];
    const float* Wy  = (const float*)d_in[4];
    const float* Bh  = (const float*)d_in[5];
    const float* By  = (const float*)d_in[6];

    float* out  = (float*)d_out;
    float* hfin = out + (size_t)S_LEN * IN_SZ;

    // ws layout: [xin S*H fp32 = 16 MB][hist 4*S*H2 u32 = 32 MB]
    float*  xin  = (float*)d_ws;
    uint32* hist = (uint32*)d_ws + (size_t)S_LEN * HID;

    // sentinel-fill hist: 0x7F byte -> each fp16 half = NaN (never produced)
    hipMemsetAsync(hist, 0x7F, (size_t)NLAY * S_LEN * H2 * sizeof(uint32), stream);

    // xin = x @ Wx^T  (M=S, N=H, K=IN)
    gemm_xin<<<dim3(HID / 64, S_LEN / 64), 256, 0, stream>>>(
        x, Wx, xin, S_LEN, HID, IN_SZ);

    // the sequential scan (persistent, 1 WG per CU)
    rnn_scan<<<NWG, BLK, 0, stream>>>(Wh, Whh, xin, Bh, hfin, hist);

    // ys = H3 @ Wy^T + By  -> d_out
    gemm_out<<<dim3(IN_SZ / 64, S_LEN / 64), 256, 0, stream>>>(
        hist + (size_t)3 * S_LEN * H2, Wy, By, out);
}